// Round 11
// baseline (1367.403 us; speedup 1.0000x reference)
//
#include <hip/hip_runtime.h>
#include <math.h>

// N=100000 nodes, E=1600000 edges, HID=64, C=2, fp32.
// Hard-won constraints (R2-R10):
//  * Weights staged in LDS before unrolled gemm cores (global-weight unrolled
//    loads -> VGPR hoist -> spill; R2/R3 WRITE 1-3GB).
//  * option-A epi demand ~224 VGPR; option-C (4x4) >256 -> spill (R6).
//  * 512-thread blocks unusable (LB(512)/LB(512,2) both cap VGPR at 128 ->
//    spill, R5/R7). Only 256-thread blocks (default 256 cap) are spill-free.
//  * k_epi: combined-weight form (R10) = 2 gemm cores, 43.5KB LDS, 127us,
//    jointly VALU(tanh)/LDS-bound.
//  * R10 counters: k_fill WRITE=105MB for 6.4MB of csr = 64B-line write
//    amplification from 4B random scatter.
// R11: bucket the CSR fill. Edges radix-partitioned by col>>7 (782 buckets,
// ~8KB csr window each): k_bcount/k_bscan/k_bscatter produce bucket-ordered
// (row,col) pairs (dense region writes), then k_fill2 = one block per bucket
// writes csr with block-exclusive windows (no cross-XCD line sharing).
// pairs buffer aliases h (dead before k_mlp writes h).

__device__ __forceinline__ void fma4(float (&acc)[4], float a, const float4& w) {
    acc[0] = fmaf(a, w.x, acc[0]);
    acc[1] = fmaf(a, w.y, acc[1]);
    acc[2] = fmaf(a, w.z, acc[2]);
    acc[3] = fmaf(a, w.w, acc[3]);
}

// 256 threads: stage 32 rows x 64 cols (8 floats/thread)
__device__ __forceinline__ void load_rows32(const float* __restrict__ src, int row0, int n,
                                            float (*dst)[68], int t)
{
    int e = t * 8;
    int r = e >> 6, i = e & 63;
    int grow = row0 + r;
    float4 v0 = make_float4(0.f, 0.f, 0.f, 0.f), v1 = v0;
    if (grow < n) {
        const float* p = src + (size_t)grow * 64 + i;
        v0 = *(const float4*)p;
        v1 = *(const float4*)(p + 4);
    }
    *(float4*)&dst[r][i]     = v0;
    *(float4*)&dst[r][i + 4] = v1;
}

// ---- option A core: 2 rows x 4 cols ----
__device__ __forceinline__ void gemm_core(const float (*in)[68], const float* w,
                                          const float* b, int rg, int cg,
                                          float (&acc0)[4], float (&acc1)[4])
{
#pragma unroll
    for (int dc = 0; dc < 4; dc++) { float bb = b[4*cg + dc]; acc0[dc] = bb; acc1[dc] = bb; }
    const int r0 = 2 * rg, r1 = 2 * rg + 1;
#pragma unroll
    for (int i = 0; i < 64; i += 4) {
        float4 a0 = *(const float4*)&in[r0][i];
        float4 a1 = *(const float4*)&in[r1][i];
        float4 q0 = *(const float4*)&w[(i + 0) * 64 + 4 * cg];
        float4 q1 = *(const float4*)&w[(i + 1) * 64 + 4 * cg];
        float4 q2 = *(const float4*)&w[(i + 2) * 64 + 4 * cg];
        float4 q3 = *(const float4*)&w[(i + 3) * 64 + 4 * cg];
        fma4(acc0, a0.x, q0); fma4(acc0, a0.y, q1); fma4(acc0, a0.z, q2); fma4(acc0, a0.w, q3);
        fma4(acc1, a1.x, q0); fma4(acc1, a1.y, q1); fma4(acc1, a1.z, q2); fma4(acc1, a1.w, q3);
    }
}

template <int MODE>  // 0=none, 1=relu, 2=tanh
__device__ __forceinline__ void gemm_lds(const float (*in)[68], const float* w,
                                         const float* b, float (*out)[68],
                                         int rg, int cg)
{
    float a0[4], a1[4];
    gemm_core(in, w, b, rg, cg, a0, a1);
#pragma unroll
    for (int dc = 0; dc < 4; dc++) {
        float v0 = a0[dc], v1 = a1[dc];
        if (MODE == 1) { v0 = fmaxf(v0, 0.f); v1 = fmaxf(v1, 0.f); }
        if (MODE == 2) { v0 = tanhf(v0); v1 = tanhf(v1); }
        a0[dc] = v0; a1[dc] = v1;
    }
    *(float4*)&out[2 * rg][4 * cg]     = make_float4(a0[0], a0[1], a0[2], a0[3]);
    *(float4*)&out[2 * rg + 1][4 * cg] = make_float4(a1[0], a1[1], a1[2], a1[3]);
}

// ---------------- CSR build ----------------

__global__ __launch_bounds__(256) void k_zero(int* __restrict__ arr, int n1)
{
    int i = blockIdx.x * 256 + threadIdx.x;
    if (i < n1) arr[i] = 0;
}

__global__ __launch_bounds__(256) void k_count(const int* __restrict__ col, int* __restrict__ arr, int e)
{
    int i = blockIdx.x * 256 + threadIdx.x;
    if (i < e) atomicAdd(&arr[col[i]], 1);
}

// bucket histogram (bucket = col>>7)
__global__ __launch_bounds__(256) void k_bcount(const int* __restrict__ col, int* __restrict__ barr, int e)
{
    int i = blockIdx.x * 256 + threadIdx.x;
    if (i < e) atomicAdd(&barr[col[i] >> 7], 1);
}

// single-block exclusive scan of barr[0..nbk) (nbk <= 1024)
__global__ __launch_bounds__(256) void k_bscan(int* __restrict__ barr, int nbk)
{
    __shared__ int s[256];
    int t = threadIdx.x;
    int c0 = t * 4;
    int v[4]; int sum = 0;
#pragma unroll
    for (int j = 0; j < 4; j++) { v[j] = (c0 + j < nbk) ? barr[c0 + j] : 0; sum += v[j]; }
    s[t] = sum;
    __syncthreads();
    for (int d = 1; d < 256; d <<= 1) {
        int u = (t >= d) ? s[t - d] : 0;
        __syncthreads();
        s[t] += u;
        __syncthreads();
    }
    int run = s[t] - sum;
#pragma unroll
    for (int j = 0; j < 4; j++) {
        if (c0 + j < nbk) { barr[c0 + j] = run; run += v[j]; }
    }
}

// scatter (row,col) pairs into bucket-ordered buffer; barr advances to ends
__global__ __launch_bounds__(256) void k_bscatter(const int* __restrict__ row, const int* __restrict__ col,
                                                  int* __restrict__ barr, int2* __restrict__ pairs, int e)
{
    int i = blockIdx.x * 256 + threadIdx.x;
    if (i < e) {
        int c = col[i];
        int p = atomicAdd(&barr[c >> 7], 1);
        pairs[p] = make_int2(row[i], c);
    }
}

// node-level scan (3-kernel hierarchy)
__global__ __launch_bounds__(256) void k_scan_a(int* __restrict__ arr, int* __restrict__ part, int n)
{
    __shared__ int s[256];
    int b = blockIdx.x, t = threadIdx.x;
    int i0 = b * 512 + 2 * t, i1 = i0 + 1;
    int v0 = (i0 < n) ? arr[i0] : 0;
    int v1 = (i1 < n) ? arr[i1] : 0;
    int sum = v0 + v1;
    s[t] = sum;
    __syncthreads();
    for (int d = 1; d < 256; d <<= 1) {
        int v = (t >= d) ? s[t - d] : 0;
        __syncthreads();
        s[t] += v;
        __syncthreads();
    }
    int excl = s[t] - sum;
    if (i0 < n) arr[i0] = excl;
    if (i1 < n) arr[i1] = excl + v0;
    if (t == 255) part[b] = s[255];
}

__global__ __launch_bounds__(256) void k_scan_b(int* __restrict__ part, int nb)
{
    __shared__ int s[256];
    int t = threadIdx.x;
    int v = (t < nb) ? part[t] : 0;
    s[t] = v;
    __syncthreads();
    for (int d = 1; d < 256; d <<= 1) {
        int u = (t >= d) ? s[t - d] : 0;
        __syncthreads();
        s[t] += u;
        __syncthreads();
    }
    if (t < nb) part[t] = s[t] - v;
}

__global__ __launch_bounds__(256) void k_scan_c(int* __restrict__ arr, const int* __restrict__ part, int n)
{
    int i = blockIdx.x * 256 + threadIdx.x;
    if (i < n) arr[i] += part[i >> 9];
}

// one block per bucket: csr writes confined to this bucket's ~8KB window.
// after this: arr[c] = end of segment c ; start(c) = c ? arr[c-1] : 0
__global__ __launch_bounds__(256) void k_fill2(const int2* __restrict__ pairs,
                                               const int* __restrict__ barr,
                                               int* __restrict__ arr, int* __restrict__ csr)
{
    int b = blockIdx.x;
    int start = (b == 0) ? 0 : barr[b - 1];
    int end = barr[b];
    for (int i = start + threadIdx.x; i < end; i += 256) {
        int2 pr = pairs[i];
        int p = atomicAdd(&arr[pr.y], 1);
        csr[p] = pr.x;
    }
}

// ---------------- weight precombination ----------------
// pre layout (floats): W0[4096] | W1[4096] | c0[64]@8192 | c1[64]@8256 |
//                      u0[128]@8320 | u1[128]@8448 | v[4]@8576

__global__ __launch_bounds__(256) void k_pre(
    const float* __restrict__ wg1, const float* __restrict__ bg1,
    const float* __restrict__ wg2, const float* __restrict__ bg2,
    const float* __restrict__ wf,  const float* __restrict__ bf,
    const float* __restrict__ wc,  float* __restrict__ pre)
{
    __shared__ float wfs[4096];
    __shared__ float wcs[128];
    int t = threadIdx.x;
    for (int i = t; i < 4096; i += 256) wfs[i] = wf[i];
    if (t < 128) wcs[t] = wc[t];
    __syncthreads();
    int i = t & 63, jb = (t >> 6) * 16;
    float acc0[16], acc1[16];
#pragma unroll
    for (int j = 0; j < 16; j++) { acc0[j] = 0.f; acc1[j] = 0.f; }
#pragma unroll 1
    for (int k = 0; k < 64; k++) {
        float a = wg1[i * 64 + k];
        float b = wg2[i * 64 + k];
#pragma unroll
        for (int j = 0; j < 16; j++) {
            float w = wfs[k * 64 + jb + j];
            acc0[j] = fmaf(a, w, acc0[j]);
            acc1[j] = fmaf(b, w, acc1[j]);
        }
    }
#pragma unroll
    for (int j = 0; j < 16; j++) {
        pre[i * 64 + jb + j]        = acc0[j];
        pre[4096 + i * 64 + jb + j] = acc1[j];
    }
    if (t < 64) {
        float s0 = bf[t], s1 = bf[t];
#pragma unroll 1
        for (int m = 0; m < 64; m++) {
            s0 = fmaf(bg1[m], wfs[m * 64 + t], s0);
            s1 = fmaf(bg2[m], wfs[m * 64 + t], s1);
        }
        pre[8192 + t] = s0;
        pre[8256 + t] = s1;
        float u00 = 0.f, u01 = 0.f, u10 = 0.f, u11 = 0.f;
#pragma unroll 1
        for (int m = 0; m < 64; m++) {
            float g1 = wg1[t * 64 + m], g2 = wg2[t * 64 + m];
            u00 = fmaf(g1, wcs[m * 2 + 0], u00);
            u01 = fmaf(g1, wcs[m * 2 + 1], u01);
            u10 = fmaf(g2, wcs[m * 2 + 0], u10);
            u11 = fmaf(g2, wcs[m * 2 + 1], u11);
        }
        pre[8320 + t * 2]     = u00;
        pre[8320 + t * 2 + 1] = u01;
        pre[8448 + t * 2]     = u10;
        pre[8448 + t * 2 + 1] = u11;
    }
    if (t == 0) {
        float v00 = 0.f, v01 = 0.f, v10 = 0.f, v11 = 0.f;
#pragma unroll 1
        for (int m = 0; m < 64; m++) {
            v00 = fmaf(bg1[m], wcs[m * 2 + 0], v00);
            v01 = fmaf(bg1[m], wcs[m * 2 + 1], v01);
            v10 = fmaf(bg2[m], wcs[m * 2 + 0], v10);
            v11 = fmaf(bg2[m], wcs[m * 2 + 1], v11);
        }
        pre[8576] = v00; pre[8577] = v01; pre[8578] = v10; pre[8579] = v11;
    }
}

// ---------------- node MLP + fused per-node scalars ----------------

__global__ __launch_bounds__(256) void k_mlp(const float* __restrict__ x,
    const float* __restrict__ w1, const float* __restrict__ b1,
    const float* __restrict__ w2, const float* __restrict__ b2,
    const float* __restrict__ w3, const float* __restrict__ b3,
    const int* __restrict__ arr, float* __restrict__ h,
    float2* __restrict__ nrm2, int n)
{
    __shared__ float w1s[4096], w2s[4096], w3s[4096];
    __shared__ float b1s[64], b2s[64], b3s[64];
    __shared__ float xs[32][68], hs[32][68];
    int t = threadIdx.x;
    for (int i = t; i < 4096; i += 256) { w1s[i] = w1[i]; w2s[i] = w2[i]; w3s[i] = w3[i]; }
    if (t < 64) { b1s[t] = b1[t]; b2s[t] = b2[t]; b3s[t] = b3[t]; }
    __syncthreads();
    int cg = t & 15, rg = t >> 4;
    for (int row0 = blockIdx.x * 32; row0 < n; row0 += gridDim.x * 32) {
        load_rows32(x, row0, n, xs, t);
        __syncthreads();
        gemm_lds<1>(xs, w1s, b1s, hs, rg, cg);
        __syncthreads();
        gemm_lds<1>(hs, w2s, b2s, xs, rg, cg);
        __syncthreads();
        {
            float a0[4], a1[4];
            gemm_core(xs, w3s, b3s, rg, cg, a0, a1);
            int r0 = row0 + 2 * rg, r1 = r0 + 1;
            if (r0 < n) *(float4*)&h[(size_t)r0 * 64 + 4 * cg] = make_float4(a0[0], a0[1], a0[2], a0[3]);
            if (r1 < n) *(float4*)&h[(size_t)r1 * 64 + 4 * cg] = make_float4(a1[0], a1[1], a1[2], a1[3]);
            float s0 = a0[0]*a0[0] + a0[1]*a0[1] + a0[2]*a0[2] + a0[3]*a0[3];
            float s1 = a1[0]*a1[0] + a1[1]*a1[1] + a1[2]*a1[2] + a1[3]*a1[3];
#pragma unroll
            for (int d = 1; d < 16; d <<= 1) { s0 += __shfl_xor(s0, d, 64); s1 += __shfl_xor(s1, d, 64); }
            if (cg == 0) {
                if (r0 < n) {
                    int st = (r0 == 0) ? 0 : arr[r0 - 1];
                    nrm2[r0] = make_float2(1.0f / (sqrtf(s0) + 1e-12f),
                                           rsqrtf((float)(arr[r0] - st + 1)));
                }
                if (r1 < n) {
                    int st = arr[r1 - 1];
                    nrm2[r1] = make_float2(1.0f / (sqrtf(s1) + 1e-12f),
                                           rsqrtf((float)(arr[r1] - st + 1)));
                }
            }
        }
        __syncthreads();
    }
}

// ---------------- edge pass: wave/node, 8 edge-groups x 8 lanes ----------------

__global__ __launch_bounds__(256) void k_gather(const float* __restrict__ h,
    const int* __restrict__ arr, const int* __restrict__ csr,
    const float2* __restrict__ nrm2, const float* __restrict__ beta_p,
    const float* __restrict__ wc,
    float* __restrict__ agg, float2* __restrict__ yp, int n)
{
    int node = blockIdx.x * 4 + (threadIdx.x >> 6);
    if (node >= n) return;
    int lane = threadIdx.x & 63;
    int g = lane >> 3, s = lane & 7;
    float beta = beta_p[0];
    const float4* hrow = (const float4*)(h + (size_t)node * 64);
    float4 hcA = hrow[2 * s];
    float4 hcB = hrow[2 * s + 1];
    float ss = hcA.x*hcA.x + hcA.y*hcA.y + hcA.z*hcA.z + hcA.w*hcA.w
             + hcB.x*hcB.x + hcB.y*hcB.y + hcB.z*hcB.z + hcB.w*hcB.w;
#pragma unroll
    for (int d = 1; d < 8; d <<= 1) ss += __shfl_xor(ss, d, 64);
    float2 nc = nrm2[node];
    float rnc = nc.x, dc = nc.y;
    float wself = expf(beta * ss * rnc * rnc);
    float4 aA = make_float4(0.f,0.f,0.f,0.f), aB = aA, nA = aA, nB = aA;
    float denom = 0.f;
    if (g == 0) {
        aA = make_float4(dc*hcA.x, dc*hcA.y, dc*hcA.z, dc*hcA.w);
        aB = make_float4(dc*hcB.x, dc*hcB.y, dc*hcB.z, dc*hcB.w);
        nA = make_float4(wself*hcA.x, wself*hcA.y, wself*hcA.z, wself*hcA.w);
        nB = make_float4(wself*hcB.x, wself*hcB.y, wself*hcB.z, wself*hcB.w);
        denom = wself;
    }
    int start = (node == 0) ? 0 : arr[node - 1];
    int end = arr[node];
#pragma unroll 1
    for (int k0 = start; k0 < end; k0 += 64) {
        int m = min(64, end - k0);
        int idx = 0; float rv = 0.f, dv = 0.f;
        if (lane < m) {
            idx = csr[k0 + lane];
            float2 nd = nrm2[idx];
            rv = nd.x; dv = nd.y;
        }
        int ei = __shfl(idx, g, 64);
        const float4* rp = (const float4*)(h + (size_t)ei * 64);
        float4 cA = rp[2 * s], cB = rp[2 * s + 1];
#pragma unroll 1
        for (int k = 0; k < m; k += 8) {
            float4 hA = cA, hB = cB;
            if (k + 8 < m) {
                int e2 = __shfl(idx, k + 8 + g, 64);
                const float4* p2 = (const float4*)(h + (size_t)e2 * 64);
                cA = p2[2 * s]; cB = p2[2 * s + 1];
            }
            float rnr = __shfl(rv, k + g, 64);
            float dvr = __shfl(dv, k + g, 64);
            float p = hA.x*hcA.x + hA.y*hcA.y + hA.z*hcA.z + hA.w*hcA.w
                    + hB.x*hcB.x + hB.y*hcB.y + hB.z*hcB.z + hB.w*hcB.w;
#pragma unroll
            for (int d = 1; d < 8; d <<= 1) p += __shfl_xor(p, d, 64);
            bool act = (k + g) < m;
            float w   = act ? expf(beta * p * rnc * rnr) : 0.f;
            float dve = act ? dvr : 0.f;
            aA.x = fmaf(dve, hA.x, aA.x); aA.y = fmaf(dve, hA.y, aA.y);
            aA.z = fmaf(dve, hA.z, aA.z); aA.w = fmaf(dve, hA.w, aA.w);
            aB.x = fmaf(dve, hB.x, aB.x); aB.y = fmaf(dve, hB.y, aB.y);
            aB.z = fmaf(dve, hB.z, aB.z); aB.w = fmaf(dve, hB.w, aB.w);
            nA.x = fmaf(w, hA.x, nA.x); nA.y = fmaf(w, hA.y, nA.y);
            nA.z = fmaf(w, hA.z, nA.z); nA.w = fmaf(w, hA.w, nA.w);
            nB.x = fmaf(w, hB.x, nB.x); nB.y = fmaf(w, hB.y, nB.y);
            nB.z = fmaf(w, hB.z, nB.z); nB.w = fmaf(w, hB.w, nB.w);
            denom += w;
        }
    }
#pragma unroll
    for (int d = 8; d < 64; d <<= 1) {
        aA.x += __shfl_xor(aA.x, d, 64); aA.y += __shfl_xor(aA.y, d, 64);
        aA.z += __shfl_xor(aA.z, d, 64); aA.w += __shfl_xor(aA.w, d, 64);
        aB.x += __shfl_xor(aB.x, d, 64); aB.y += __shfl_xor(aB.y, d, 64);
        aB.z += __shfl_xor(aB.z, d, 64); aB.w += __shfl_xor(aB.w, d, 64);
        nA.x += __shfl_xor(nA.x, d, 64); nA.y += __shfl_xor(nA.y, d, 64);
        nA.z += __shfl_xor(nA.z, d, 64); nA.w += __shfl_xor(nA.w, d, 64);
        nB.x += __shfl_xor(nB.x, d, 64); nB.y += __shfl_xor(nB.y, d, 64);
        nB.z += __shfl_xor(nB.z, d, 64); nB.w += __shfl_xor(nB.w, d, 64);
        denom += __shfl_xor(denom, d, 64);
    }
    if (g == 0) {
        float4* op = (float4*)(agg + (size_t)node * 64);
        op[2 * s]     = make_float4(dc*aA.x, dc*aA.y, dc*aA.z, dc*aA.w);
        op[2 * s + 1] = make_float4(dc*aB.x, dc*aB.y, dc*aB.z, dc*aB.w);
    }
    float inv = 1.0f / denom;
    float cx = 0.f, cy = 0.f;
#pragma unroll
    for (int j = 0; j < 4; j++) {
        float2 wa = ((const float2*)wc)[64 + 8 * s + j];
        float2 wb = ((const float2*)wc)[64 + 8 * s + 4 + j];
        float va = (&nA.x)[j], vb = (&nB.x)[j];
        cx = fmaf(va, wa.x, cx); cx = fmaf(vb, wb.x, cx);
        cy = fmaf(va, wa.y, cy); cy = fmaf(vb, wb.y, cy);
    }
    cx *= inv; cy *= inv;
#pragma unroll
    for (int d = 1; d < 8; d <<= 1) { cx += __shfl_xor(cx, d, 64); cy += __shfl_xor(cy, d, 64); }
    if (lane == 0) yp[node] = make_float2(cx, cy);
}

// ---------------- xp pass: h <- tanh(h@wx + bx) in place ----------------

__global__ __launch_bounds__(256) void k_xp(float* __restrict__ h,
    const float* __restrict__ wx, const float* __restrict__ bx, int n)
{
    __shared__ float wxs[4096];
    __shared__ float bxs[64];
    __shared__ float xs[32][68];
    int t = threadIdx.x;
    for (int i = t; i < 4096; i += 256) wxs[i] = wx[i];
    if (t < 64) bxs[t] = bx[t];
    __syncthreads();
    int cg = t & 15, rg = t >> 4;
    for (int row0 = blockIdx.x * 32; row0 < n; row0 += gridDim.x * 32) {
        load_rows32(h, row0, n, xs, t);
        __syncthreads();
        float a0[4], a1[4];
        gemm_core(xs, wxs, bxs, rg, cg, a0, a1);
#pragma unroll
        for (int j = 0; j < 4; j++) { a0[j] = tanhf(a0[j]); a1[j] = tanhf(a1[j]); }
        int r0 = row0 + 2 * rg, r1 = r0 + 1;
        if (r0 < n) *(float4*)&h[(size_t)r0 * 64 + 4 * cg] = make_float4(a0[0], a0[1], a0[2], a0[3]);
        if (r1 < n) *(float4*)&h[(size_t)r1 * 64 + 4 * cg] = make_float4(a1[0], a1[1], a1[2], a1[3]);
        __syncthreads();
    }
}

// ---------------- epilogue (combined weights): 2 gemm cores + 64->2 dots ----------------

__global__ __launch_bounds__(256) void k_epi(const float* __restrict__ agg,
    const float* __restrict__ xpb, const float2* __restrict__ yp,
    const float* __restrict__ pre, const float* __restrict__ bc,
    float* __restrict__ y, int n, int ntiles)
{
    __shared__ float W0s[4096], W1s[4096];
    __shared__ float c0s[64], c1s[64], us[256], vs[4], bcs[2];
    __shared__ float A[32][68];
    int t = threadIdx.x;
    for (int i = t; i < 4096; i += 256) { W0s[i] = pre[i]; W1s[i] = pre[4096 + i]; }
    if (t < 64) { c0s[t] = pre[8192 + t]; c1s[t] = pre[8256 + t]; }
    us[t] = pre[8320 + t];
    if (t < 4) vs[t] = pre[8576 + t];
    if (t < 2) bcs[t] = bc[t];
    __syncthreads();
    int cg = t & 15, rg = t >> 4;
    for (int tile = blockIdx.x; tile < ntiles; tile += gridDim.x) {
        int row0 = tile * 32;
        load_rows32(agg, row0, n, A, t);
        __syncthreads();
        int r0g = row0 + 2 * rg, r1g = r0g + 1;
        float4 xq0 = make_float4(0.f,0.f,0.f,0.f), xq1 = xq0;
        if (r0g < n) xq0 = *(const float4*)&xpb[(size_t)r0g * 64 + 4 * cg];
        if (r1g < n) xq1 = *(const float4*)&xpb[(size_t)r1g * 64 + 4 * cg];
        float a0[4], a1[4];
        gemm_core(A, W0s, c0s, rg, cg, a0, a1);
        float l00 = 0.f, l01 = 0.f;
        l00 = fmaf(tanhf(a0[0]), xq0.x, l00); l00 = fmaf(tanhf(a0[1]), xq0.y, l00);
        l00 = fmaf(tanhf(a0[2]), xq0.z, l00); l00 = fmaf(tanhf(a0[3]), xq0.w, l00);
        l01 = fmaf(tanhf(a1[0]), xq1.x, l01); l01 = fmaf(tanhf(a1[1]), xq1.y, l01);
        l01 = fmaf(tanhf(a1[2]), xq1.z, l01); l01 = fmaf(tanhf(a1[3]), xq1.w, l01);
        gemm_core(A, W1s, c1s, rg, cg, a0, a1);
        float l10 = 0.f, l11 = 0.f;
        l10 = fmaf(tanhf(a0[0]), xq0.x, l10); l10 = fmaf(tanhf(a0[1]), xq0.y, l10);
        l10 = fmaf(tanhf(a0[2]), xq0.z, l10); l10 = fmaf(tanhf(a0[3]), xq0.w, l10);
        l11 = fmaf(tanhf(a1[0]), xq1.x, l11); l11 = fmaf(tanhf(a1[1]), xq1.y, l11);
        l11 = fmaf(tanhf(a1[2]), xq1.z, l11); l11 = fmaf(tanhf(a1[3]), xq1.w, l11);
        float4 av0 = *(const float4*)&A[2 * rg][4 * cg];
        float4 av1 = *(const float4*)&A[2 * rg + 1][4 * cg];
        float za0=0.f, za1=0.f, zb0=0.f, zb1=0.f;
        float zc0=0.f, zc1=0.f, zd0=0.f, zd1=0.f;
#pragma unroll
        for (int j = 0; j < 4; j++) {
            int k = 4 * cg + j;
            float u0c0 = us[k * 2], u0c1 = us[k * 2 + 1];
            float u1c0 = us[128 + k * 2], u1c1 = us[128 + k * 2 + 1];
            float p0 = (&av0.x)[j], p1 = (&av1.x)[j];
            za0 = fmaf(p0, u0c0, za0); za1 = fmaf(p0, u0c1, za1);
            zb0 = fmaf(p0, u1c0, zb0); zb1 = fmaf(p0, u1c1, zb1);
            zc0 = fmaf(p1, u0c0, zc0); zc1 = fmaf(p1, u0c1, zc1);
            zd0 = fmaf(p1, u1c0, zd0); zd1 = fmaf(p1, u1c1, zd1);
        }
#pragma unroll
        for (int d = 1; d < 16; d <<= 1) {
            l00 += __shfl_xor(l00, d, 64); l01 += __shfl_xor(l01, d, 64);
            l10 += __shfl_xor(l10, d, 64); l11 += __shfl_xor(l11, d, 64);
            za0 += __shfl_xor(za0, d, 64); za1 += __shfl_xor(za1, d, 64);
            zb0 += __shfl_xor(zb0, d, 64); zb1 += __shfl_xor(zb1, d, 64);
            zc0 += __shfl_xor(zc0, d, 64); zc1 += __shfl_xor(zc1, d, 64);
            zd0 += __shfl_xor(zd0, d, 64); zd1 += __shfl_xor(zd1, d, 64);
        }
        if (cg == 0) {
            if (r0g < n) {
                float mx = fmaxf(l00, l10);
                float e0 = expf(l00 - mx), e1 = expf(l10 - mx);
                float inv = 1.0f / (e0 + e1);
                float s0 = e0 * inv, s1 = e1 * inv;
                float2 ypv = yp[r0g];
                float y0v = s0 * (za0 + vs[0]) + s1 * (zb0 + vs[2]) + ypv.x + bcs[0];
                float y1v = s0 * (za1 + vs[1]) + s1 * (zb1 + vs[3]) + ypv.y + bcs[1];
                *(float2*)&y[(size_t)r0g * 2] = make_float2(y0v, y1v);
            }
            if (r1g < n) {
                float mx = fmaxf(l01, l11);
                float e0 = expf(l01 - mx), e1 = expf(l11 - mx);
                float inv = 1.0f / (e0 + e1);
                float s0 = e0 * inv, s1 = e1 * inv;
                float2 ypv = yp[r1g];
                float y0v = s0 * (zc0 + vs[0]) + s1 * (zd0 + vs[2]) + ypv.x + bcs[0];
                float y1v = s0 * (zc1 + vs[1]) + s1 * (zd1 + vs[3]) + ypv.y + bcs[1];
                *(float2*)&y[(size_t)r1g * 2] = make_float2(y0v, y1v);
            }
        }
        __syncthreads();
    }
}

extern "C" void kernel_launch(void* const* d_in, const int* in_sizes, int n_in,
                              void* d_out, int out_size, void* d_ws, size_t ws_size,
                              hipStream_t stream)
{
    const float* x    = (const float*)d_in[0];
    const int*   ei   = (const int*)d_in[1];
    const float* w1   = (const float*)d_in[2];
    const float* b1   = (const float*)d_in[3];
    const float* w2   = (const float*)d_in[4];
    const float* b2   = (const float*)d_in[5];
    const float* w3   = (const float*)d_in[6];
    const float* b3   = (const float*)d_in[7];
    const float* wg1  = (const float*)d_in[8];
    const float* bg1  = (const float*)d_in[9];
    const float* wg2  = (const float*)d_in[10];
    const float* bg2  = (const float*)d_in[11];
    const float* beta = (const float*)d_in[12];
    const float* wf   = (const float*)d_in[13];
    const float* bf   = (const float*)d_in[14];
    const float* wx   = (const float*)d_in[15];
    const float* bx   = (const float*)d_in[16];
    const float* wc   = (const float*)d_in[17];
    const float* bc   = (const float*)d_in[18];
    float* y = (float*)d_out;

    int n = in_sizes[0] / 64;     // 100000
    int e = in_sizes[1] / 2;      // 1600000
    const int* row = ei;
    const int* col = ei + e;

    // workspace ~34MB
    char* p = (char*)d_ws;
    auto alloc = [&](size_t bytes) { char* q = p; p += (bytes + 255) & ~(size_t)255; return q; };
    float*  h    = (float*)alloc((size_t)n * 64 * 4);    // 25.6MB (pairs -> h -> xp)
    int*    csr  = (int*)alloc((size_t)e * 4);           // 6.4MB
    float2* nrm2 = (float2*)alloc((size_t)n * 8);        // 0.8MB
    int*    arr  = (int*)alloc((size_t)(n + 1) * 4);     // 0.4MB
    float2* yp   = (float2*)alloc((size_t)n * 8);        // 0.8MB
    int*    part = (int*)alloc(1024 * 4);                // node-scan block totals
    float*  pre  = (float*)alloc(8704 * 4);              // combined weights
    int*    barr = (int*)alloc(1024 * 4);                // bucket counters

    // pairs buffer (12.8MB) aliases h: dead before k_mlp writes h.
    int2* pairs = (int2*)h;
    // agg reuses x's buffer (x dead after k_mlp; harness restores d_in).
    float* agg = (float*)d_in[0];

    int ntiles_e = (n + 31) / 32;          // 3125
    int nb = (n + 511) / 512;              // 196 node-scan blocks
    int nbk = (n + 127) / 128;             // 782 buckets

    k_pre<<<1, 256, 0, stream>>>(wg1, bg1, wg2, bg2, wf, bf, wc, pre);
    k_zero<<<(n + 256) / 256, 256, 0, stream>>>(arr, n + 1);
    k_zero<<<4, 256, 0, stream>>>(barr, nbk);
    k_bcount<<<(e + 255) / 256, 256, 0, stream>>>(col, barr, e);
    k_bscan<<<1, 256, 0, stream>>>(barr, nbk);
    k_bscatter<<<(e + 255) / 256, 256, 0, stream>>>(row, col, barr, pairs, e);
    k_count<<<(e + 255) / 256, 256, 0, stream>>>(col, arr, e);
    k_scan_a<<<nb, 256, 0, stream>>>(arr, part, n);
    k_scan_b<<<1, 256, 0, stream>>>(part, nb);
    k_scan_c<<<(n + 255) / 256, 256, 0, stream>>>(arr, part, n);
    k_fill2<<<nbk, 256, 0, stream>>>(pairs, barr, arr, csr);
    k_mlp<<<800, 256, 0, stream>>>(x, w1, b1, w2, b2, w3, b3, arr, h, nrm2, n);
    k_gather<<<(n + 3) / 4, 256, 0, stream>>>(h, arr, csr, nrm2, beta, wc, agg, yp, n);
    k_xp<<<800, 256, 0, stream>>>(h, wx, bx, n);
    k_epi<<<1024, 256, 0, stream>>>(agg, h, yp, pre, bc, y, n, ntiles_e);
}

// Round 12
// 615.616 us; speedup vs baseline: 2.2212x; 2.2212x over previous
//
#include <hip/hip_runtime.h>
#include <math.h>

// N=100000 nodes, E=1600000 edges, HID=64, C=2, fp32.
// Hard-won constraints (R2-R11):
//  * Weights staged in LDS before unrolled gemm cores (global-weight unrolled
//    loads -> VGPR hoist -> spill; R2/R3 WRITE 1-3GB).
//  * option-A epi demand ~224 VGPR; option-C (4x4) >256 -> spill (R6).
//  * 512-thread blocks unusable (LB(512)/LB(512,2) both cap VGPR at 128 ->
//    spill, R5/R7). Only 256-thread blocks (default 256 cap) are spill-free.
//  * k_epi: combined-weight form (R10) = 2 gemm cores, 43.5KB LDS.
//  * k_fill 4B random scatter: 64B-line write amplification (105MB for 6.4MB
//    csr). R11's two-phase bucket scatter was WORSE (pair-scatter has the
//    same amplification + 782-counter atomic contention; 377us) -> reverted.
// R12: R10 structure + (a) nontemporal csr store in k_fill, (b) fast tanh
// ((e^2x-1)/(e^2x+1), native __expf, clamp +-15) in k_epi/k_xp, (c) __expf
// in k_gather.

__device__ __forceinline__ float fast_tanh(float x) {
    x = fminf(fmaxf(x, -15.f), 15.f);
    float e = __expf(2.f * x);
    return (e - 1.f) * __frcp_rn(e + 1.f);
}

__device__ __forceinline__ void fma4(float (&acc)[4], float a, const float4& w) {
    acc[0] = fmaf(a, w.x, acc[0]);
    acc[1] = fmaf(a, w.y, acc[1]);
    acc[2] = fmaf(a, w.z, acc[2]);
    acc[3] = fmaf(a, w.w, acc[3]);
}

// 256 threads: stage 32 rows x 64 cols (8 floats/thread)
__device__ __forceinline__ void load_rows32(const float* __restrict__ src, int row0, int n,
                                            float (*dst)[68], int t)
{
    int e = t * 8;
    int r = e >> 6, i = e & 63;
    int grow = row0 + r;
    float4 v0 = make_float4(0.f, 0.f, 0.f, 0.f), v1 = v0;
    if (grow < n) {
        const float* p = src + (size_t)grow * 64 + i;
        v0 = *(const float4*)p;
        v1 = *(const float4*)(p + 4);
    }
    *(float4*)&dst[r][i]     = v0;
    *(float4*)&dst[r][i + 4] = v1;
}

// ---- option A core: 2 rows x 4 cols ----
__device__ __forceinline__ void gemm_core(const float (*in)[68], const float* w,
                                          const float* b, int rg, int cg,
                                          float (&acc0)[4], float (&acc1)[4])
{
#pragma unroll
    for (int dc = 0; dc < 4; dc++) { float bb = b[4*cg + dc]; acc0[dc] = bb; acc1[dc] = bb; }
    const int r0 = 2 * rg, r1 = 2 * rg + 1;
#pragma unroll
    for (int i = 0; i < 64; i += 4) {
        float4 a0 = *(const float4*)&in[r0][i];
        float4 a1 = *(const float4*)&in[r1][i];
        float4 q0 = *(const float4*)&w[(i + 0) * 64 + 4 * cg];
        float4 q1 = *(const float4*)&w[(i + 1) * 64 + 4 * cg];
        float4 q2 = *(const float4*)&w[(i + 2) * 64 + 4 * cg];
        float4 q3 = *(const float4*)&w[(i + 3) * 64 + 4 * cg];
        fma4(acc0, a0.x, q0); fma4(acc0, a0.y, q1); fma4(acc0, a0.z, q2); fma4(acc0, a0.w, q3);
        fma4(acc1, a1.x, q0); fma4(acc1, a1.y, q1); fma4(acc1, a1.z, q2); fma4(acc1, a1.w, q3);
    }
}

template <int MODE>  // 0=none, 1=relu
__device__ __forceinline__ void gemm_lds(const float (*in)[68], const float* w,
                                         const float* b, float (*out)[68],
                                         int rg, int cg)
{
    float a0[4], a1[4];
    gemm_core(in, w, b, rg, cg, a0, a1);
#pragma unroll
    for (int dc = 0; dc < 4; dc++) {
        float v0 = a0[dc], v1 = a1[dc];
        if (MODE == 1) { v0 = fmaxf(v0, 0.f); v1 = fmaxf(v1, 0.f); }
        a0[dc] = v0; a1[dc] = v1;
    }
    *(float4*)&out[2 * rg][4 * cg]     = make_float4(a0[0], a0[1], a0[2], a0[3]);
    *(float4*)&out[2 * rg + 1][4 * cg] = make_float4(a1[0], a1[1], a1[2], a1[3]);
}

// ---------------- CSR build (single arr[n+1], hierarchical scan) ----------------

__global__ __launch_bounds__(256) void k_zero(int* __restrict__ arr, int n1)
{
    int i = blockIdx.x * 256 + threadIdx.x;
    if (i < n1) arr[i] = 0;
}

__global__ __launch_bounds__(256) void k_count(const int* __restrict__ col, int* __restrict__ arr, int e)
{
    int i = blockIdx.x * 256 + threadIdx.x;
    if (i < e) atomicAdd(&arr[col[i]], 1);
}

__global__ __launch_bounds__(256) void k_scan_a(int* __restrict__ arr, int* __restrict__ part, int n)
{
    __shared__ int s[256];
    int b = blockIdx.x, t = threadIdx.x;
    int i0 = b * 512 + 2 * t, i1 = i0 + 1;
    int v0 = (i0 < n) ? arr[i0] : 0;
    int v1 = (i1 < n) ? arr[i1] : 0;
    int sum = v0 + v1;
    s[t] = sum;
    __syncthreads();
    for (int d = 1; d < 256; d <<= 1) {
        int v = (t >= d) ? s[t - d] : 0;
        __syncthreads();
        s[t] += v;
        __syncthreads();
    }
    int excl = s[t] - sum;
    if (i0 < n) arr[i0] = excl;
    if (i1 < n) arr[i1] = excl + v0;
    if (t == 255) part[b] = s[255];
}

__global__ __launch_bounds__(256) void k_scan_b(int* __restrict__ part, int nb)
{
    __shared__ int s[256];
    int t = threadIdx.x;
    int v = (t < nb) ? part[t] : 0;
    s[t] = v;
    __syncthreads();
    for (int d = 1; d < 256; d <<= 1) {
        int u = (t >= d) ? s[t - d] : 0;
        __syncthreads();
        s[t] += u;
        __syncthreads();
    }
    if (t < nb) part[t] = s[t] - v;
}

__global__ __launch_bounds__(256) void k_scan_c(int* __restrict__ arr, const int* __restrict__ part, int n)
{
    int i = blockIdx.x * 256 + threadIdx.x;
    if (i < n) arr[i] += part[i >> 9];
}

// after fill: arr[c] = end of segment c ; start(c) = c ? arr[c-1] : 0
__global__ __launch_bounds__(256) void k_fill(const int* __restrict__ row, const int* __restrict__ col,
                                              int* __restrict__ arr, int* __restrict__ csr, int e)
{
    int i = blockIdx.x * 256 + threadIdx.x;
    if (i < e) {
        int c = col[i];
        int p = atomicAdd(&arr[c], 1);
        __builtin_nontemporal_store(row[i], &csr[p]);
    }
}

// ---------------- weight precombination ----------------
// pre layout (floats): W0[4096] | W1[4096] | c0[64]@8192 | c1[64]@8256 |
//                      u0[128]@8320 | u1[128]@8448 | v[4]@8576

__global__ __launch_bounds__(256) void k_pre(
    const float* __restrict__ wg1, const float* __restrict__ bg1,
    const float* __restrict__ wg2, const float* __restrict__ bg2,
    const float* __restrict__ wf,  const float* __restrict__ bf,
    const float* __restrict__ wc,  float* __restrict__ pre)
{
    __shared__ float wfs[4096];
    __shared__ float wcs[128];
    int t = threadIdx.x;
    for (int i = t; i < 4096; i += 256) wfs[i] = wf[i];
    if (t < 128) wcs[t] = wc[t];
    __syncthreads();
    int i = t & 63, jb = (t >> 6) * 16;
    float acc0[16], acc1[16];
#pragma unroll
    for (int j = 0; j < 16; j++) { acc0[j] = 0.f; acc1[j] = 0.f; }
#pragma unroll 1
    for (int k = 0; k < 64; k++) {
        float a = wg1[i * 64 + k];
        float b = wg2[i * 64 + k];
#pragma unroll
        for (int j = 0; j < 16; j++) {
            float w = wfs[k * 64 + jb + j];
            acc0[j] = fmaf(a, w, acc0[j]);
            acc1[j] = fmaf(b, w, acc1[j]);
        }
    }
#pragma unroll
    for (int j = 0; j < 16; j++) {
        pre[i * 64 + jb + j]        = acc0[j];
        pre[4096 + i * 64 + jb + j] = acc1[j];
    }
    if (t < 64) {
        float s0 = bf[t], s1 = bf[t];
#pragma unroll 1
        for (int m = 0; m < 64; m++) {
            s0 = fmaf(bg1[m], wfs[m * 64 + t], s0);
            s1 = fmaf(bg2[m], wfs[m * 64 + t], s1);
        }
        pre[8192 + t] = s0;
        pre[8256 + t] = s1;
        float u00 = 0.f, u01 = 0.f, u10 = 0.f, u11 = 0.f;
#pragma unroll 1
        for (int m = 0; m < 64; m++) {
            float g1 = wg1[t * 64 + m], g2 = wg2[t * 64 + m];
            u00 = fmaf(g1, wcs[m * 2 + 0], u00);
            u01 = fmaf(g1, wcs[m * 2 + 1], u01);
            u10 = fmaf(g2, wcs[m * 2 + 0], u10);
            u11 = fmaf(g2, wcs[m * 2 + 1], u11);
        }
        pre[8320 + t * 2]     = u00;
        pre[8320 + t * 2 + 1] = u01;
        pre[8448 + t * 2]     = u10;
        pre[8448 + t * 2 + 1] = u11;
    }
    if (t == 0) {
        float v00 = 0.f, v01 = 0.f, v10 = 0.f, v11 = 0.f;
#pragma unroll 1
        for (int m = 0; m < 64; m++) {
            v00 = fmaf(bg1[m], wcs[m * 2 + 0], v00);
            v01 = fmaf(bg1[m], wcs[m * 2 + 1], v01);
            v10 = fmaf(bg2[m], wcs[m * 2 + 0], v10);
            v11 = fmaf(bg2[m], wcs[m * 2 + 1], v11);
        }
        pre[8576] = v00; pre[8577] = v01; pre[8578] = v10; pre[8579] = v11;
    }
}

// ---------------- node MLP + fused per-node scalars ----------------

__global__ __launch_bounds__(256) void k_mlp(const float* __restrict__ x,
    const float* __restrict__ w1, const float* __restrict__ b1,
    const float* __restrict__ w2, const float* __restrict__ b2,
    const float* __restrict__ w3, const float* __restrict__ b3,
    const int* __restrict__ arr, float* __restrict__ h,
    float2* __restrict__ nrm2, int n)
{
    __shared__ float w1s[4096], w2s[4096], w3s[4096];
    __shared__ float b1s[64], b2s[64], b3s[64];
    __shared__ float xs[32][68], hs[32][68];
    int t = threadIdx.x;
    for (int i = t; i < 4096; i += 256) { w1s[i] = w1[i]; w2s[i] = w2[i]; w3s[i] = w3[i]; }
    if (t < 64) { b1s[t] = b1[t]; b2s[t] = b2[t]; b3s[t] = b3[t]; }
    __syncthreads();
    int cg = t & 15, rg = t >> 4;
    for (int row0 = blockIdx.x * 32; row0 < n; row0 += gridDim.x * 32) {
        load_rows32(x, row0, n, xs, t);
        __syncthreads();
        gemm_lds<1>(xs, w1s, b1s, hs, rg, cg);
        __syncthreads();
        gemm_lds<1>(hs, w2s, b2s, xs, rg, cg);
        __syncthreads();
        {
            float a0[4], a1[4];
            gemm_core(xs, w3s, b3s, rg, cg, a0, a1);
            int r0 = row0 + 2 * rg, r1 = r0 + 1;
            if (r0 < n) *(float4*)&h[(size_t)r0 * 64 + 4 * cg] = make_float4(a0[0], a0[1], a0[2], a0[3]);
            if (r1 < n) *(float4*)&h[(size_t)r1 * 64 + 4 * cg] = make_float4(a1[0], a1[1], a1[2], a1[3]);
            float s0 = a0[0]*a0[0] + a0[1]*a0[1] + a0[2]*a0[2] + a0[3]*a0[3];
            float s1 = a1[0]*a1[0] + a1[1]*a1[1] + a1[2]*a1[2] + a1[3]*a1[3];
#pragma unroll
            for (int d = 1; d < 16; d <<= 1) { s0 += __shfl_xor(s0, d, 64); s1 += __shfl_xor(s1, d, 64); }
            if (cg == 0) {
                if (r0 < n) {
                    int st = (r0 == 0) ? 0 : arr[r0 - 1];
                    nrm2[r0] = make_float2(1.0f / (sqrtf(s0) + 1e-12f),
                                           rsqrtf((float)(arr[r0] - st + 1)));
                }
                if (r1 < n) {
                    int st = arr[r1 - 1];
                    nrm2[r1] = make_float2(1.0f / (sqrtf(s1) + 1e-12f),
                                           rsqrtf((float)(arr[r1] - st + 1)));
                }
            }
        }
        __syncthreads();
    }
}

// ---------------- edge pass: wave/node, 8 edge-groups x 8 lanes ----------------

__global__ __launch_bounds__(256) void k_gather(const float* __restrict__ h,
    const int* __restrict__ arr, const int* __restrict__ csr,
    const float2* __restrict__ nrm2, const float* __restrict__ beta_p,
    const float* __restrict__ wc,
    float* __restrict__ agg, float2* __restrict__ yp, int n)
{
    int node = blockIdx.x * 4 + (threadIdx.x >> 6);
    if (node >= n) return;
    int lane = threadIdx.x & 63;
    int g = lane >> 3, s = lane & 7;
    float beta = beta_p[0];
    const float4* hrow = (const float4*)(h + (size_t)node * 64);
    float4 hcA = hrow[2 * s];
    float4 hcB = hrow[2 * s + 1];
    float ss = hcA.x*hcA.x + hcA.y*hcA.y + hcA.z*hcA.z + hcA.w*hcA.w
             + hcB.x*hcB.x + hcB.y*hcB.y + hcB.z*hcB.z + hcB.w*hcB.w;
#pragma unroll
    for (int d = 1; d < 8; d <<= 1) ss += __shfl_xor(ss, d, 64);
    float2 nc = nrm2[node];
    float rnc = nc.x, dc = nc.y;
    float wself = __expf(beta * ss * rnc * rnc);
    float4 aA = make_float4(0.f,0.f,0.f,0.f), aB = aA, nA = aA, nB = aA;
    float denom = 0.f;
    if (g == 0) {
        aA = make_float4(dc*hcA.x, dc*hcA.y, dc*hcA.z, dc*hcA.w);
        aB = make_float4(dc*hcB.x, dc*hcB.y, dc*hcB.z, dc*hcB.w);
        nA = make_float4(wself*hcA.x, wself*hcA.y, wself*hcA.z, wself*hcA.w);
        nB = make_float4(wself*hcB.x, wself*hcB.y, wself*hcB.z, wself*hcB.w);
        denom = wself;
    }
    int start = (node == 0) ? 0 : arr[node - 1];
    int end = arr[node];
#pragma unroll 1
    for (int k0 = start; k0 < end; k0 += 64) {
        int m = min(64, end - k0);
        int idx = 0; float rv = 0.f, dv = 0.f;
        if (lane < m) {
            idx = csr[k0 + lane];
            float2 nd = nrm2[idx];
            rv = nd.x; dv = nd.y;
        }
        int ei = __shfl(idx, g, 64);
        const float4* rp = (const float4*)(h + (size_t)ei * 64);
        float4 cA = rp[2 * s], cB = rp[2 * s + 1];
#pragma unroll 1
        for (int k = 0; k < m; k += 8) {
            float4 hA = cA, hB = cB;
            if (k + 8 < m) {
                int e2 = __shfl(idx, k + 8 + g, 64);
                const float4* p2 = (const float4*)(h + (size_t)e2 * 64);
                cA = p2[2 * s]; cB = p2[2 * s + 1];
            }
            float rnr = __shfl(rv, k + g, 64);
            float dvr = __shfl(dv, k + g, 64);
            float p = hA.x*hcA.x + hA.y*hcA.y + hA.z*hcA.z + hA.w*hcA.w
                    + hB.x*hcB.x + hB.y*hcB.y + hB.z*hcB.z + hB.w*hcB.w;
#pragma unroll
            for (int d = 1; d < 8; d <<= 1) p += __shfl_xor(p, d, 64);
            bool act = (k + g) < m;
            float w   = act ? __expf(beta * p * rnc * rnr) : 0.f;
            float dve = act ? dvr : 0.f;
            aA.x = fmaf(dve, hA.x, aA.x); aA.y = fmaf(dve, hA.y, aA.y);
            aA.z = fmaf(dve, hA.z, aA.z); aA.w = fmaf(dve, hA.w, aA.w);
            aB.x = fmaf(dve, hB.x, aB.x); aB.y = fmaf(dve, hB.y, aB.y);
            aB.z = fmaf(dve, hB.z, aB.z); aB.w = fmaf(dve, hB.w, aB.w);
            nA.x = fmaf(w, hA.x, nA.x); nA.y = fmaf(w, hA.y, nA.y);
            nA.z = fmaf(w, hA.z, nA.z); nA.w = fmaf(w, hA.w, nA.w);
            nB.x = fmaf(w, hB.x, nB.x); nB.y = fmaf(w, hB.y, nB.y);
            nB.z = fmaf(w, hB.z, nB.z); nB.w = fmaf(w, hB.w, nB.w);
            denom += w;
        }
    }
#pragma unroll
    for (int d = 8; d < 64; d <<= 1) {
        aA.x += __shfl_xor(aA.x, d, 64); aA.y += __shfl_xor(aA.y, d, 64);
        aA.z += __shfl_xor(aA.z, d, 64); aA.w += __shfl_xor(aA.w, d, 64);
        aB.x += __shfl_xor(aB.x, d, 64); aB.y += __shfl_xor(aB.y, d, 64);
        aB.z += __shfl_xor(aB.z, d, 64); aB.w += __shfl_xor(aB.w, d, 64);
        nA.x += __shfl_xor(nA.x, d, 64); nA.y += __shfl_xor(nA.y, d, 64);
        nA.z += __shfl_xor(nA.z, d, 64); nA.w += __shfl_xor(nA.w, d, 64);
        nB.x += __shfl_xor(nB.x, d, 64); nB.y += __shfl_xor(nB.y, d, 64);
        nB.z += __shfl_xor(nB.z, d, 64); nB.w += __shfl_xor(nB.w, d, 64);
        denom += __shfl_xor(denom, d, 64);
    }
    if (g == 0) {
        float4* op = (float4*)(agg + (size_t)node * 64);
        op[2 * s]     = make_float4(dc*aA.x, dc*aA.y, dc*aA.z, dc*aA.w);
        op[2 * s + 1] = make_float4(dc*aB.x, dc*aB.y, dc*aB.z, dc*aB.w);
    }
    float inv = 1.0f / denom;
    float cx = 0.f, cy = 0.f;
#pragma unroll
    for (int j = 0; j < 4; j++) {
        float2 wa = ((const float2*)wc)[64 + 8 * s + j];
        float2 wb = ((const float2*)wc)[64 + 8 * s + 4 + j];
        float va = (&nA.x)[j], vb = (&nB.x)[j];
        cx = fmaf(va, wa.x, cx); cx = fmaf(vb, wb.x, cx);
        cy = fmaf(va, wa.y, cy); cy = fmaf(vb, wb.y, cy);
    }
    cx *= inv; cy *= inv;
#pragma unroll
    for (int d = 1; d < 8; d <<= 1) { cx += __shfl_xor(cx, d, 64); cy += __shfl_xor(cy, d, 64); }
    if (lane == 0) yp[node] = make_float2(cx, cy);
}

// ---------------- xp pass: h <- tanh(h@wx + bx) in place ----------------

__global__ __launch_bounds__(256) void k_xp(float* __restrict__ h,
    const float* __restrict__ wx, const float* __restrict__ bx, int n)
{
    __shared__ float wxs[4096];
    __shared__ float bxs[64];
    __shared__ float xs[32][68];
    int t = threadIdx.x;
    for (int i = t; i < 4096; i += 256) wxs[i] = wx[i];
    if (t < 64) bxs[t] = bx[t];
    __syncthreads();
    int cg = t & 15, rg = t >> 4;
    for (int row0 = blockIdx.x * 32; row0 < n; row0 += gridDim.x * 32) {
        load_rows32(h, row0, n, xs, t);
        __syncthreads();
        float a0[4], a1[4];
        gemm_core(xs, wxs, bxs, rg, cg, a0, a1);
#pragma unroll
        for (int j = 0; j < 4; j++) { a0[j] = fast_tanh(a0[j]); a1[j] = fast_tanh(a1[j]); }
        int r0 = row0 + 2 * rg, r1 = r0 + 1;
        if (r0 < n) *(float4*)&h[(size_t)r0 * 64 + 4 * cg] = make_float4(a0[0], a0[1], a0[2], a0[3]);
        if (r1 < n) *(float4*)&h[(size_t)r1 * 64 + 4 * cg] = make_float4(a1[0], a1[1], a1[2], a1[3]);
        __syncthreads();
    }
}

// ---------------- epilogue (combined weights): 2 gemm cores + 64->2 dots ----------------

__global__ __launch_bounds__(256) void k_epi(const float* __restrict__ agg,
    const float* __restrict__ xpb, const float2* __restrict__ yp,
    const float* __restrict__ pre, const float* __restrict__ bc,
    float* __restrict__ y, int n, int ntiles)
{
    __shared__ float W0s[4096], W1s[4096];
    __shared__ float c0s[64], c1s[64], us[256], vs[4], bcs[2];
    __shared__ float A[32][68];
    int t = threadIdx.x;
    for (int i = t; i < 4096; i += 256) { W0s[i] = pre[i]; W1s[i] = pre[4096 + i]; }
    if (t < 64) { c0s[t] = pre[8192 + t]; c1s[t] = pre[8256 + t]; }
    us[t] = pre[8320 + t];
    if (t < 4) vs[t] = pre[8576 + t];
    if (t < 2) bcs[t] = bc[t];
    __syncthreads();
    int cg = t & 15, rg = t >> 4;
    for (int tile = blockIdx.x; tile < ntiles; tile += gridDim.x) {
        int row0 = tile * 32;
        load_rows32(agg, row0, n, A, t);
        __syncthreads();
        int r0g = row0 + 2 * rg, r1g = r0g + 1;
        float4 xq0 = make_float4(0.f,0.f,0.f,0.f), xq1 = xq0;
        if (r0g < n) xq0 = *(const float4*)&xpb[(size_t)r0g * 64 + 4 * cg];
        if (r1g < n) xq1 = *(const float4*)&xpb[(size_t)r1g * 64 + 4 * cg];
        float a0[4], a1[4];
        gemm_core(A, W0s, c0s, rg, cg, a0, a1);
        float l00 = 0.f, l01 = 0.f;
        l00 = fmaf(fast_tanh(a0[0]), xq0.x, l00); l00 = fmaf(fast_tanh(a0[1]), xq0.y, l00);
        l00 = fmaf(fast_tanh(a0[2]), xq0.z, l00); l00 = fmaf(fast_tanh(a0[3]), xq0.w, l00);
        l01 = fmaf(fast_tanh(a1[0]), xq1.x, l01); l01 = fmaf(fast_tanh(a1[1]), xq1.y, l01);
        l01 = fmaf(fast_tanh(a1[2]), xq1.z, l01); l01 = fmaf(fast_tanh(a1[3]), xq1.w, l01);
        gemm_core(A, W1s, c1s, rg, cg, a0, a1);
        float l10 = 0.f, l11 = 0.f;
        l10 = fmaf(fast_tanh(a0[0]), xq0.x, l10); l10 = fmaf(fast_tanh(a0[1]), xq0.y, l10);
        l10 = fmaf(fast_tanh(a0[2]), xq0.z, l10); l10 = fmaf(fast_tanh(a0[3]), xq0.w, l10);
        l11 = fmaf(fast_tanh(a1[0]), xq1.x, l11); l11 = fmaf(fast_tanh(a1[1]), xq1.y, l11);
        l11 = fmaf(fast_tanh(a1[2]), xq1.z, l11); l11 = fmaf(fast_tanh(a1[3]), xq1.w, l11);
        float4 av0 = *(const float4*)&A[2 * rg][4 * cg];
        float4 av1 = *(const float4*)&A[2 * rg + 1][4 * cg];
        float za0=0.f, za1=0.f, zb0=0.f, zb1=0.f;
        float zc0=0.f, zc1=0.f, zd0=0.f, zd1=0.f;
#pragma unroll
        for (int j = 0; j < 4; j++) {
            int k = 4 * cg + j;
            float u0c0 = us[k * 2], u0c1 = us[k * 2 + 1];
            float u1c0 = us[128 + k * 2], u1c1 = us[128 + k * 2 + 1];
            float p0 = (&av0.x)[j], p1 = (&av1.x)[j];
            za0 = fmaf(p0, u0c0, za0); za1 = fmaf(p0, u0c1, za1);
            zb0 = fmaf(p0, u1c0, zb0); zb1 = fmaf(p0, u1c1, zb1);
            zc0 = fmaf(p1, u0c0, zc0); zc1 = fmaf(p1, u0c1, zc1);
            zd0 = fmaf(p1, u1c0, zd0); zd1 = fmaf(p1, u1c1, zd1);
        }
#pragma unroll
        for (int d = 1; d < 16; d <<= 1) {
            l00 += __shfl_xor(l00, d, 64); l01 += __shfl_xor(l01, d, 64);
            l10 += __shfl_xor(l10, d, 64); l11 += __shfl_xor(l11, d, 64);
            za0 += __shfl_xor(za0, d, 64); za1 += __shfl_xor(za1, d, 64);
            zb0 += __shfl_xor(zb0, d, 64); zb1 += __shfl_xor(zb1, d, 64);
            zc0 += __shfl_xor(zc0, d, 64); zc1 += __shfl_xor(zc1, d, 64);
            zd0 += __shfl_xor(zd0, d, 64); zd1 += __shfl_xor(zd1, d, 64);
        }
        if (cg == 0) {
            if (r0g < n) {
                float mx = fmaxf(l00, l10);
                float e0 = __expf(l00 - mx), e1 = __expf(l10 - mx);
                float inv = 1.0f / (e0 + e1);
                float s0 = e0 * inv, s1 = e1 * inv;
                float2 ypv = yp[r0g];
                float y0v = s0 * (za0 + vs[0]) + s1 * (zb0 + vs[2]) + ypv.x + bcs[0];
                float y1v = s0 * (za1 + vs[1]) + s1 * (zb1 + vs[3]) + ypv.y + bcs[1];
                *(float2*)&y[(size_t)r0g * 2] = make_float2(y0v, y1v);
            }
            if (r1g < n) {
                float mx = fmaxf(l01, l11);
                float e0 = __expf(l01 - mx), e1 = __expf(l11 - mx);
                float inv = 1.0f / (e0 + e1);
                float s0 = e0 * inv, s1 = e1 * inv;
                float2 ypv = yp[r1g];
                float y0v = s0 * (zc0 + vs[0]) + s1 * (zd0 + vs[2]) + ypv.x + bcs[0];
                float y1v = s0 * (zc1 + vs[1]) + s1 * (zd1 + vs[3]) + ypv.y + bcs[1];
                *(float2*)&y[(size_t)r1g * 2] = make_float2(y0v, y1v);
            }
        }
        __syncthreads();
    }
}

extern "C" void kernel_launch(void* const* d_in, const int* in_sizes, int n_in,
                              void* d_out, int out_size, void* d_ws, size_t ws_size,
                              hipStream_t stream)
{
    const float* x    = (const float*)d_in[0];
    const int*   ei   = (const int*)d_in[1];
    const float* w1   = (const float*)d_in[2];
    const float* b1   = (const float*)d_in[3];
    const float* w2   = (const float*)d_in[4];
    const float* b2   = (const float*)d_in[5];
    const float* w3   = (const float*)d_in[6];
    const float* b3   = (const float*)d_in[7];
    const float* wg1  = (const float*)d_in[8];
    const float* bg1  = (const float*)d_in[9];
    const float* wg2  = (const float*)d_in[10];
    const float* bg2  = (const float*)d_in[11];
    const float* beta = (const float*)d_in[12];
    const float* wf   = (const float*)d_in[13];
    const float* bf   = (const float*)d_in[14];
    const float* wx   = (const float*)d_in[15];
    const float* bx   = (const float*)d_in[16];
    const float* wc   = (const float*)d_in[17];
    const float* bc   = (const float*)d_in[18];
    float* y = (float*)d_out;

    int n = in_sizes[0] / 64;     // 100000
    int e = in_sizes[1] / 2;      // 1600000
    const int* row = ei;
    const int* col = ei + e;

    // workspace ~34MB
    char* p = (char*)d_ws;
    auto alloc = [&](size_t bytes) { char* q = p; p += (bytes + 255) & ~(size_t)255; return q; };
    float*  h    = (float*)alloc((size_t)n * 64 * 4);    // 25.6MB (h, then xp in-place)
    int*    csr  = (int*)alloc((size_t)e * 4);           // 6.4MB
    float2* nrm2 = (float2*)alloc((size_t)n * 8);        // 0.8MB
    int*    arr  = (int*)alloc((size_t)(n + 1) * 4);     // 0.4MB
    float2* yp   = (float2*)alloc((size_t)n * 8);        // 0.8MB
    int*    part = (int*)alloc(1024 * 4);                // node-scan block totals
    float*  pre  = (float*)alloc(8704 * 4);              // combined weights

    // agg reuses x's buffer (x dead after k_mlp; harness restores d_in).
    float* agg = (float*)d_in[0];

    int ntiles_e = (n + 31) / 32;          // 3125
    int nb = (n + 511) / 512;              // 196 node-scan blocks

    k_pre<<<1, 256, 0, stream>>>(wg1, bg1, wg2, bg2, wf, bf, wc, pre);
    k_zero<<<(n + 256) / 256, 256, 0, stream>>>(arr, n + 1);
    k_count<<<(e + 255) / 256, 256, 0, stream>>>(col, arr, e);
    k_scan_a<<<nb, 256, 0, stream>>>(arr, part, n);
    k_scan_b<<<1, 256, 0, stream>>>(part, nb);
    k_scan_c<<<(n + 255) / 256, 256, 0, stream>>>(arr, part, n);
    k_fill<<<(e + 255) / 256, 256, 0, stream>>>(row, col, arr, csr, e);
    k_mlp<<<800, 256, 0, stream>>>(x, w1, b1, w2, b2, w3, b3, arr, h, nrm2, n);
    k_gather<<<(n + 3) / 4, 256, 0, stream>>>(h, arr, csr, nrm2, beta, wc, agg, yp, n);
    k_xp<<<800, 256, 0, stream>>>(h, wx, bx, n);
    k_epi<<<1024, 256, 0, stream>>>(agg, h, yp, pre, bc, y, n, ntiles_e);
}

// Round 13
// 499.070 us; speedup vs baseline: 2.7399x; 1.2335x over previous
//
#include <hip/hip_runtime.h>
#include <math.h>

// N=100000 nodes, E=1600000 edges, HID=64, C=2, fp32.
// Hard-won constraints (R2-R12):
//  * Weights staged in LDS before unrolled gemm cores (global-weight unrolled
//    loads -> VGPR hoist -> spill; R2/R3 WRITE 1-3GB).
//  * 512-thread blocks unusable (VGPR cap 128 regardless of launch_bounds
//    form -> spill). Only 256-thread blocks (default 256 cap) are spill-free.
//  * k_epi: combined-weight form (R10) + fast_tanh (R12).
//  * Random 4B scatter/atomics are transaction-bound, not BW-bound: k_fill
//    was 132us, WRITE 108MB for 6.4MB of csr; NT store = no change (R12).
//    R11's UNSTAGED pair scatter had the same amplification (79MB, 377us).
// R13: proper LDS-staged bucket sort for the CSR build:
//   k_bhist    per-block LDS hist of 196 buckets (col>>9) -> 19K global atomics
//   k_bscan    scan bucket totals -> bases + cursors
//   k_bscatter2 8192-edge tiles, LDS-binned pairs, ONE atomicAdd per
//              bucket per tile, coalesced run copy-out (~660B runs)
//   k_fill3    one block per bucket: LDS node-hist + scan -> arr directly
//              (k_count / node scans DELETED), csr scatter via LDS cursors
//              into the bucket's 64KB window (L2-merged)

#define SCT 8192   // edges per scatter tile

__device__ __forceinline__ float fast_tanh(float x) {
    x = fminf(fmaxf(x, -15.f), 15.f);
    float e = __expf(2.f * x);
    return (e - 1.f) * __frcp_rn(e + 1.f);
}

__device__ __forceinline__ void fma4(float (&acc)[4], float a, const float4& w) {
    acc[0] = fmaf(a, w.x, acc[0]);
    acc[1] = fmaf(a, w.y, acc[1]);
    acc[2] = fmaf(a, w.z, acc[2]);
    acc[3] = fmaf(a, w.w, acc[3]);
}

// 256 threads: stage 32 rows x 64 cols (8 floats/thread)
__device__ __forceinline__ void load_rows32(const float* __restrict__ src, int row0, int n,
                                            float (*dst)[68], int t)
{
    int e = t * 8;
    int r = e >> 6, i = e & 63;
    int grow = row0 + r;
    float4 v0 = make_float4(0.f, 0.f, 0.f, 0.f), v1 = v0;
    if (grow < n) {
        const float* p = src + (size_t)grow * 64 + i;
        v0 = *(const float4*)p;
        v1 = *(const float4*)(p + 4);
    }
    *(float4*)&dst[r][i]     = v0;
    *(float4*)&dst[r][i + 4] = v1;
}

// ---- option A core: 2 rows x 4 cols ----
__device__ __forceinline__ void gemm_core(const float (*in)[68], const float* w,
                                          const float* b, int rg, int cg,
                                          float (&acc0)[4], float (&acc1)[4])
{
#pragma unroll
    for (int dc = 0; dc < 4; dc++) { float bb = b[4*cg + dc]; acc0[dc] = bb; acc1[dc] = bb; }
    const int r0 = 2 * rg, r1 = 2 * rg + 1;
#pragma unroll
    for (int i = 0; i < 64; i += 4) {
        float4 a0 = *(const float4*)&in[r0][i];
        float4 a1 = *(const float4*)&in[r1][i];
        float4 q0 = *(const float4*)&w[(i + 0) * 64 + 4 * cg];
        float4 q1 = *(const float4*)&w[(i + 1) * 64 + 4 * cg];
        float4 q2 = *(const float4*)&w[(i + 2) * 64 + 4 * cg];
        float4 q3 = *(const float4*)&w[(i + 3) * 64 + 4 * cg];
        fma4(acc0, a0.x, q0); fma4(acc0, a0.y, q1); fma4(acc0, a0.z, q2); fma4(acc0, a0.w, q3);
        fma4(acc1, a1.x, q0); fma4(acc1, a1.y, q1); fma4(acc1, a1.z, q2); fma4(acc1, a1.w, q3);
    }
}

template <int MODE>  // 0=none, 1=relu
__device__ __forceinline__ void gemm_lds(const float (*in)[68], const float* w,
                                         const float* b, float (*out)[68],
                                         int rg, int cg)
{
    float a0[4], a1[4];
    gemm_core(in, w, b, rg, cg, a0, a1);
#pragma unroll
    for (int dc = 0; dc < 4; dc++) {
        float v0 = a0[dc], v1 = a1[dc];
        if (MODE == 1) { v0 = fmaxf(v0, 0.f); v1 = fmaxf(v1, 0.f); }
        a0[dc] = v0; a1[dc] = v1;
    }
    *(float4*)&out[2 * rg][4 * cg]     = make_float4(a0[0], a0[1], a0[2], a0[3]);
    *(float4*)&out[2 * rg + 1][4 * cg] = make_float4(a1[0], a1[1], a1[2], a1[3]);
}

// ---------------- CSR build: LDS-staged bucket sort ----------------

__global__ __launch_bounds__(256) void k_zero(int* __restrict__ arr, int n1)
{
    int i = blockIdx.x * 256 + threadIdx.x;
    if (i < n1) arr[i] = 0;
}

// per-tile LDS histogram of buckets (bucket = col>>9), 1 global atomic/bucket
__global__ __launch_bounds__(256) void k_bhist(const int* __restrict__ col,
                                               int* __restrict__ bhist, int e)
{
    __shared__ int hist[256];
    int t = threadIdx.x;
    hist[t] = 0;
    __syncthreads();
    int base = blockIdx.x * SCT;
    int end = min(e, base + SCT);
    for (int i = base + t; i < end; i += 256)
        atomicAdd(&hist[col[i] >> 9], 1);
    __syncthreads();
    if (hist[t]) atomicAdd(&bhist[t], hist[t]);
}

// exclusive scan of bucket totals -> bases + working cursors
__global__ __launch_bounds__(256) void k_bscan(const int* __restrict__ bhist,
                                               int* __restrict__ bbase, int* __restrict__ bcur)
{
    __shared__ int s[256];
    int t = threadIdx.x;
    int v = bhist[t];
    s[t] = v;
    __syncthreads();
    for (int d = 1; d < 256; d <<= 1) {
        int u = (t >= d) ? s[t - d] : 0;
        __syncthreads();
        s[t] += u;
        __syncthreads();
    }
    int b = s[t] - v;
    bbase[t] = b;
    bcur[t] = b;
}

// tile -> LDS bucket-binned pairs -> one reservation per bucket -> coalesced copy-out
__global__ __launch_bounds__(256) void k_bscatter2(const int* __restrict__ row,
    const int* __restrict__ col, int* __restrict__ bcur,
    int2* __restrict__ pairs, int e, int nbk)
{
    __shared__ int hist[256], lcur[256], gb[256], s[256];
    __shared__ int2 buf[SCT];
    int t = threadIdx.x;
    int base = blockIdx.x * SCT;
    int end = min(e, base + SCT);
    hist[t] = 0;
    __syncthreads();
    for (int i = base + t; i < end; i += 256)
        atomicAdd(&hist[col[i] >> 9], 1);
    __syncthreads();
    int v = hist[t];
    s[t] = v;
    __syncthreads();
    for (int d = 1; d < 256; d <<= 1) {
        int u = (t >= d) ? s[t - d] : 0;
        __syncthreads();
        s[t] += u;
        __syncthreads();
    }
    lcur[t] = s[t] - v;          // tile-local exclusive prefix
    __syncthreads();
    for (int i = base + t; i < end; i += 256) {
        int c = col[i];
        int slot = atomicAdd(&lcur[c >> 9], 1);
        buf[slot] = make_int2(row[i], c);
    }
    if (v > 0) gb[t] = atomicAdd(&bcur[t], v);   // reserve this tile's run
    __syncthreads();
    for (int b = 0; b < nbk; b++) {
        int cnt = hist[b];
        if (cnt == 0) continue;
        int lo = s[b] - cnt;
        int go = gb[b];
        for (int j = t; j < cnt; j += 256)
            pairs[go + j] = buf[lo + j];
    }
}

// one block per bucket: node-hist + scan -> arr (end-of-segment convention),
// then csr scatter via LDS cursors into the bucket's csr window.
__global__ __launch_bounds__(256) void k_fill3(const int2* __restrict__ pairs,
    const int* __restrict__ bbase, const int* __restrict__ bhist,
    int* __restrict__ arr, int* __restrict__ csr, int n)
{
    __shared__ int nh[512], nc[512], s[256];
    int b = blockIdx.x, t = threadIdx.x;
    int pbase = bbase[b];
    int cnt = bhist[b];
    int nodebase = b << 9;
    nh[t] = 0; nh[t + 256] = 0;
    __syncthreads();
    for (int i = t; i < cnt; i += 256)
        atomicAdd(&nh[pairs[pbase + i].y - nodebase], 1);
    __syncthreads();
    int v0 = nh[2 * t], v1 = nh[2 * t + 1];
    int sum = v0 + v1;
    s[t] = sum;
    __syncthreads();
    for (int d = 1; d < 256; d <<= 1) {
        int u = (t >= d) ? s[t - d] : 0;
        __syncthreads();
        s[t] += u;
        __syncthreads();
    }
    int excl = s[t] - sum;
    int n0 = nodebase + 2 * t, n1 = n0 + 1;
    nc[2 * t]     = pbase + excl;
    nc[2 * t + 1] = pbase + excl + v0;
    if (n0 < n) arr[n0] = pbase + excl + v0;
    if (n1 < n) arr[n1] = pbase + excl + v0 + v1;
    __syncthreads();
    for (int i = t; i < cnt; i += 256) {
        int2 pr = pairs[pbase + i];
        int p = atomicAdd(&nc[pr.y - nodebase], 1);
        csr[p] = pr.x;
    }
}

// ---------------- weight precombination ----------------
// pre layout (floats): W0[4096] | W1[4096] | c0[64]@8192 | c1[64]@8256 |
//                      u0[128]@8320 | u1[128]@8448 | v[4]@8576

__global__ __launch_bounds__(256) void k_pre(
    const float* __restrict__ wg1, const float* __restrict__ bg1,
    const float* __restrict__ wg2, const float* __restrict__ bg2,
    const float* __restrict__ wf,  const float* __restrict__ bf,
    const float* __restrict__ wc,  float* __restrict__ pre)
{
    __shared__ float wfs[4096];
    __shared__ float wcs[128];
    int t = threadIdx.x;
    for (int i = t; i < 4096; i += 256) wfs[i] = wf[i];
    if (t < 128) wcs[t] = wc[t];
    __syncthreads();
    int i = t & 63, jb = (t >> 6) * 16;
    float acc0[16], acc1[16];
#pragma unroll
    for (int j = 0; j < 16; j++) { acc0[j] = 0.f; acc1[j] = 0.f; }
#pragma unroll 1
    for (int k = 0; k < 64; k++) {
        float a = wg1[i * 64 + k];
        float b = wg2[i * 64 + k];
#pragma unroll
        for (int j = 0; j < 16; j++) {
            float w = wfs[k * 64 + jb + j];
            acc0[j] = fmaf(a, w, acc0[j]);
            acc1[j] = fmaf(b, w, acc1[j]);
        }
    }
#pragma unroll
    for (int j = 0; j < 16; j++) {
        pre[i * 64 + jb + j]        = acc0[j];
        pre[4096 + i * 64 + jb + j] = acc1[j];
    }
    if (t < 64) {
        float s0 = bf[t], s1 = bf[t];
#pragma unroll 1
        for (int m = 0; m < 64; m++) {
            s0 = fmaf(bg1[m], wfs[m * 64 + t], s0);
            s1 = fmaf(bg2[m], wfs[m * 64 + t], s1);
        }
        pre[8192 + t] = s0;
        pre[8256 + t] = s1;
        float u00 = 0.f, u01 = 0.f, u10 = 0.f, u11 = 0.f;
#pragma unroll 1
        for (int m = 0; m < 64; m++) {
            float g1 = wg1[t * 64 + m], g2 = wg2[t * 64 + m];
            u00 = fmaf(g1, wcs[m * 2 + 0], u00);
            u01 = fmaf(g1, wcs[m * 2 + 1], u01);
            u10 = fmaf(g2, wcs[m * 2 + 0], u10);
            u11 = fmaf(g2, wcs[m * 2 + 1], u11);
        }
        pre[8320 + t * 2]     = u00;
        pre[8320 + t * 2 + 1] = u01;
        pre[8448 + t * 2]     = u10;
        pre[8448 + t * 2 + 1] = u11;
    }
    if (t == 0) {
        float v00 = 0.f, v01 = 0.f, v10 = 0.f, v11 = 0.f;
#pragma unroll 1
        for (int m = 0; m < 64; m++) {
            v00 = fmaf(bg1[m], wcs[m * 2 + 0], v00);
            v01 = fmaf(bg1[m], wcs[m * 2 + 1], v01);
            v10 = fmaf(bg2[m], wcs[m * 2 + 0], v10);
            v11 = fmaf(bg2[m], wcs[m * 2 + 1], v11);
        }
        pre[8576] = v00; pre[8577] = v01; pre[8578] = v10; pre[8579] = v11;
    }
}

// ---------------- node MLP + fused per-node scalars ----------------

__global__ __launch_bounds__(256) void k_mlp(const float* __restrict__ x,
    const float* __restrict__ w1, const float* __restrict__ b1,
    const float* __restrict__ w2, const float* __restrict__ b2,
    const float* __restrict__ w3, const float* __restrict__ b3,
    const int* __restrict__ arr, float* __restrict__ h,
    float2* __restrict__ nrm2, int n)
{
    __shared__ float w1s[4096], w2s[4096], w3s[4096];
    __shared__ float b1s[64], b2s[64], b3s[64];
    __shared__ float xs[32][68], hs[32][68];
    int t = threadIdx.x;
    for (int i = t; i < 4096; i += 256) { w1s[i] = w1[i]; w2s[i] = w2[i]; w3s[i] = w3[i]; }
    if (t < 64) { b1s[t] = b1[t]; b2s[t] = b2[t]; b3s[t] = b3[t]; }
    __syncthreads();
    int cg = t & 15, rg = t >> 4;
    for (int row0 = blockIdx.x * 32; row0 < n; row0 += gridDim.x * 32) {
        load_rows32(x, row0, n, xs, t);
        __syncthreads();
        gemm_lds<1>(xs, w1s, b1s, hs, rg, cg);
        __syncthreads();
        gemm_lds<1>(hs, w2s, b2s, xs, rg, cg);
        __syncthreads();
        {
            float a0[4], a1[4];
            gemm_core(xs, w3s, b3s, rg, cg, a0, a1);
            int r0 = row0 + 2 * rg, r1 = r0 + 1;
            if (r0 < n) *(float4*)&h[(size_t)r0 * 64 + 4 * cg] = make_float4(a0[0], a0[1], a0[2], a0[3]);
            if (r1 < n) *(float4*)&h[(size_t)r1 * 64 + 4 * cg] = make_float4(a1[0], a1[1], a1[2], a1[3]);
            float s0 = a0[0]*a0[0] + a0[1]*a0[1] + a0[2]*a0[2] + a0[3]*a0[3];
            float s1 = a1[0]*a1[0] + a1[1]*a1[1] + a1[2]*a1[2] + a1[3]*a1[3];
#pragma unroll
            for (int d = 1; d < 16; d <<= 1) { s0 += __shfl_xor(s0, d, 64); s1 += __shfl_xor(s1, d, 64); }
            if (cg == 0) {
                if (r0 < n) {
                    int st = (r0 == 0) ? 0 : arr[r0 - 1];
                    nrm2[r0] = make_float2(1.0f / (sqrtf(s0) + 1e-12f),
                                           rsqrtf((float)(arr[r0] - st + 1)));
                }
                if (r1 < n) {
                    int st = arr[r1 - 1];
                    nrm2[r1] = make_float2(1.0f / (sqrtf(s1) + 1e-12f),
                                           rsqrtf((float)(arr[r1] - st + 1)));
                }
            }
        }
        __syncthreads();
    }
}

// ---------------- edge pass: wave/node, 8 edge-groups x 8 lanes ----------------

__global__ __launch_bounds__(256) void k_gather(const float* __restrict__ h,
    const int* __restrict__ arr, const int* __restrict__ csr,
    const float2* __restrict__ nrm2, const float* __restrict__ beta_p,
    const float* __restrict__ wc,
    float* __restrict__ agg, float2* __restrict__ yp, int n)
{
    int node = blockIdx.x * 4 + (threadIdx.x >> 6);
    if (node >= n) return;
    int lane = threadIdx.x & 63;
    int g = lane >> 3, s = lane & 7;
    float beta = beta_p[0];
    const float4* hrow = (const float4*)(h + (size_t)node * 64);
    float4 hcA = hrow[2 * s];
    float4 hcB = hrow[2 * s + 1];
    float ss = hcA.x*hcA.x + hcA.y*hcA.y + hcA.z*hcA.z + hcA.w*hcA.w
             + hcB.x*hcB.x + hcB.y*hcB.y + hcB.z*hcB.z + hcB.w*hcB.w;
#pragma unroll
    for (int d = 1; d < 8; d <<= 1) ss += __shfl_xor(ss, d, 64);
    float2 nc = nrm2[node];
    float rnc = nc.x, dc = nc.y;
    float wself = __expf(beta * ss * rnc * rnc);
    float4 aA = make_float4(0.f,0.f,0.f,0.f), aB = aA, nA = aA, nB = aA;
    float denom = 0.f;
    if (g == 0) {
        aA = make_float4(dc*hcA.x, dc*hcA.y, dc*hcA.z, dc*hcA.w);
        aB = make_float4(dc*hcB.x, dc*hcB.y, dc*hcB.z, dc*hcB.w);
        nA = make_float4(wself*hcA.x, wself*hcA.y, wself*hcA.z, wself*hcA.w);
        nB = make_float4(wself*hcB.x, wself*hcB.y, wself*hcB.z, wself*hcB.w);
        denom = wself;
    }
    int start = (node == 0) ? 0 : arr[node - 1];
    int end = arr[node];
#pragma unroll 1
    for (int k0 = start; k0 < end; k0 += 64) {
        int m = min(64, end - k0);
        int idx = 0; float rv = 0.f, dv = 0.f;
        if (lane < m) {
            idx = csr[k0 + lane];
            float2 nd = nrm2[idx];
            rv = nd.x; dv = nd.y;
        }
        int ei = __shfl(idx, g, 64);
        const float4* rp = (const float4*)(h + (size_t)ei * 64);
        float4 cA = rp[2 * s], cB = rp[2 * s + 1];
#pragma unroll 1
        for (int k = 0; k < m; k += 8) {
            float4 hA = cA, hB = cB;
            if (k + 8 < m) {
                int e2 = __shfl(idx, k + 8 + g, 64);
                const float4* p2 = (const float4*)(h + (size_t)e2 * 64);
                cA = p2[2 * s]; cB = p2[2 * s + 1];
            }
            float rnr = __shfl(rv, k + g, 64);
            float dvr = __shfl(dv, k + g, 64);
            float p = hA.x*hcA.x + hA.y*hcA.y + hA.z*hcA.z + hA.w*hcA.w
                    + hB.x*hcB.x + hB.y*hcB.y + hB.z*hcB.z + hB.w*hcB.w;
#pragma unroll
            for (int d = 1; d < 8; d <<= 1) p += __shfl_xor(p, d, 64);
            bool act = (k + g) < m;
            float w   = act ? __expf(beta * p * rnc * rnr) : 0.f;
            float dve = act ? dvr : 0.f;
            aA.x = fmaf(dve, hA.x, aA.x); aA.y = fmaf(dve, hA.y, aA.y);
            aA.z = fmaf(dve, hA.z, aA.z); aA.w = fmaf(dve, hA.w, aA.w);
            aB.x = fmaf(dve, hB.x, aB.x); aB.y = fmaf(dve, hB.y, aB.y);
            aB.z = fmaf(dve, hB.z, aB.z); aB.w = fmaf(dve, hB.w, aB.w);
            nA.x = fmaf(w, hA.x, nA.x); nA.y = fmaf(w, hA.y, nA.y);
            nA.z = fmaf(w, hA.z, nA.z); nA.w = fmaf(w, hA.w, nA.w);
            nB.x = fmaf(w, hB.x, nB.x); nB.y = fmaf(w, hB.y, nB.y);
            nB.z = fmaf(w, hB.z, nB.z); nB.w = fmaf(w, hB.w, nB.w);
            denom += w;
        }
    }
#pragma unroll
    for (int d = 8; d < 64; d <<= 1) {
        aA.x += __shfl_xor(aA.x, d, 64); aA.y += __shfl_xor(aA.y, d, 64);
        aA.z += __shfl_xor(aA.z, d, 64); aA.w += __shfl_xor(aA.w, d, 64);
        aB.x += __shfl_xor(aB.x, d, 64); aB.y += __shfl_xor(aB.y, d, 64);
        aB.z += __shfl_xor(aB.z, d, 64); aB.w += __shfl_xor(aB.w, d, 64);
        nA.x += __shfl_xor(nA.x, d, 64); nA.y += __shfl_xor(nA.y, d, 64);
        nA.z += __shfl_xor(nA.z, d, 64); nA.w += __shfl_xor(nA.w, d, 64);
        nB.x += __shfl_xor(nB.x, d, 64); nB.y += __shfl_xor(nB.y, d, 64);
        nB.z += __shfl_xor(nB.z, d, 64); nB.w += __shfl_xor(nB.w, d, 64);
        denom += __shfl_xor(denom, d, 64);
    }
    if (g == 0) {
        float4* op = (float4*)(agg + (size_t)node * 64);
        op[2 * s]     = make_float4(dc*aA.x, dc*aA.y, dc*aA.z, dc*aA.w);
        op[2 * s + 1] = make_float4(dc*aB.x, dc*aB.y, dc*aB.z, dc*aB.w);
    }
    float inv = 1.0f / denom;
    float cx = 0.f, cy = 0.f;
#pragma unroll
    for (int j = 0; j < 4; j++) {
        float2 wa = ((const float2*)wc)[64 + 8 * s + j];
        float2 wb = ((const float2*)wc)[64 + 8 * s + 4 + j];
        float va = (&nA.x)[j], vb = (&nB.x)[j];
        cx = fmaf(va, wa.x, cx); cx = fmaf(vb, wb.x, cx);
        cy = fmaf(va, wa.y, cy); cy = fmaf(vb, wb.y, cy);
    }
    cx *= inv; cy *= inv;
#pragma unroll
    for (int d = 1; d < 8; d <<= 1) { cx += __shfl_xor(cx, d, 64); cy += __shfl_xor(cy, d, 64); }
    if (lane == 0) yp[node] = make_float2(cx, cy);
}

// ---------------- xp pass: h <- tanh(h@wx + bx) in place ----------------

__global__ __launch_bounds__(256) void k_xp(float* __restrict__ h,
    const float* __restrict__ wx, const float* __restrict__ bx, int n)
{
    __shared__ float wxs[4096];
    __shared__ float bxs[64];
    __shared__ float xs[32][68];
    int t = threadIdx.x;
    for (int i = t; i < 4096; i += 256) wxs[i] = wx[i];
    if (t < 64) bxs[t] = bx[t];
    __syncthreads();
    int cg = t & 15, rg = t >> 4;
    for (int row0 = blockIdx.x * 32; row0 < n; row0 += gridDim.x * 32) {
        load_rows32(h, row0, n, xs, t);
        __syncthreads();
        float a0[4], a1[4];
        gemm_core(xs, wxs, bxs, rg, cg, a0, a1);
#pragma unroll
        for (int j = 0; j < 4; j++) { a0[j] = fast_tanh(a0[j]); a1[j] = fast_tanh(a1[j]); }
        int r0 = row0 + 2 * rg, r1 = r0 + 1;
        if (r0 < n) *(float4*)&h[(size_t)r0 * 64 + 4 * cg] = make_float4(a0[0], a0[1], a0[2], a0[3]);
        if (r1 < n) *(float4*)&h[(size_t)r1 * 64 + 4 * cg] = make_float4(a1[0], a1[1], a1[2], a1[3]);
        __syncthreads();
    }
}

// ---------------- epilogue (combined weights): 2 gemm cores + 64->2 dots ----------------

__global__ __launch_bounds__(256) void k_epi(const float* __restrict__ agg,
    const float* __restrict__ xpb, const float2* __restrict__ yp,
    const float* __restrict__ pre, const float* __restrict__ bc,
    float* __restrict__ y, int n, int ntiles)
{
    __shared__ float W0s[4096], W1s[4096];
    __shared__ float c0s[64], c1s[64], us[256], vs[4], bcs[2];
    __shared__ float A[32][68];
    int t = threadIdx.x;
    for (int i = t; i < 4096; i += 256) { W0s[i] = pre[i]; W1s[i] = pre[4096 + i]; }
    if (t < 64) { c0s[t] = pre[8192 + t]; c1s[t] = pre[8256 + t]; }
    us[t] = pre[8320 + t];
    if (t < 4) vs[t] = pre[8576 + t];
    if (t < 2) bcs[t] = bc[t];
    __syncthreads();
    int cg = t & 15, rg = t >> 4;
    for (int tile = blockIdx.x; tile < ntiles; tile += gridDim.x) {
        int row0 = tile * 32;
        load_rows32(agg, row0, n, A, t);
        __syncthreads();
        int r0g = row0 + 2 * rg, r1g = r0g + 1;
        float4 xq0 = make_float4(0.f,0.f,0.f,0.f), xq1 = xq0;
        if (r0g < n) xq0 = *(const float4*)&xpb[(size_t)r0g * 64 + 4 * cg];
        if (r1g < n) xq1 = *(const float4*)&xpb[(size_t)r1g * 64 + 4 * cg];
        float a0[4], a1[4];
        gemm_core(A, W0s, c0s, rg, cg, a0, a1);
        float l00 = 0.f, l01 = 0.f;
        l00 = fmaf(fast_tanh(a0[0]), xq0.x, l00); l00 = fmaf(fast_tanh(a0[1]), xq0.y, l00);
        l00 = fmaf(fast_tanh(a0[2]), xq0.z, l00); l00 = fmaf(fast_tanh(a0[3]), xq0.w, l00);
        l01 = fmaf(fast_tanh(a1[0]), xq1.x, l01); l01 = fmaf(fast_tanh(a1[1]), xq1.y, l01);
        l01 = fmaf(fast_tanh(a1[2]), xq1.z, l01); l01 = fmaf(fast_tanh(a1[3]), xq1.w, l01);
        gemm_core(A, W1s, c1s, rg, cg, a0, a1);
        float l10 = 0.f, l11 = 0.f;
        l10 = fmaf(fast_tanh(a0[0]), xq0.x, l10); l10 = fmaf(fast_tanh(a0[1]), xq0.y, l10);
        l10 = fmaf(fast_tanh(a0[2]), xq0.z, l10); l10 = fmaf(fast_tanh(a0[3]), xq0.w, l10);
        l11 = fmaf(fast_tanh(a1[0]), xq1.x, l11); l11 = fmaf(fast_tanh(a1[1]), xq1.y, l11);
        l11 = fmaf(fast_tanh(a1[2]), xq1.z, l11); l11 = fmaf(fast_tanh(a1[3]), xq1.w, l11);
        float4 av0 = *(const float4*)&A[2 * rg][4 * cg];
        float4 av1 = *(const float4*)&A[2 * rg + 1][4 * cg];
        float za0=0.f, za1=0.f, zb0=0.f, zb1=0.f;
        float zc0=0.f, zc1=0.f, zd0=0.f, zd1=0.f;
#pragma unroll
        for (int j = 0; j < 4; j++) {
            int k = 4 * cg + j;
            float u0c0 = us[k * 2], u0c1 = us[k * 2 + 1];
            float u1c0 = us[128 + k * 2], u1c1 = us[128 + k * 2 + 1];
            float p0 = (&av0.x)[j], p1 = (&av1.x)[j];
            za0 = fmaf(p0, u0c0, za0); za1 = fmaf(p0, u0c1, za1);
            zb0 = fmaf(p0, u1c0, zb0); zb1 = fmaf(p0, u1c1, zb1);
            zc0 = fmaf(p1, u0c0, zc0); zc1 = fmaf(p1, u0c1, zc1);
            zd0 = fmaf(p1, u1c0, zd0); zd1 = fmaf(p1, u1c1, zd1);
        }
#pragma unroll
        for (int d = 1; d < 16; d <<= 1) {
            l00 += __shfl_xor(l00, d, 64); l01 += __shfl_xor(l01, d, 64);
            l10 += __shfl_xor(l10, d, 64); l11 += __shfl_xor(l11, d, 64);
            za0 += __shfl_xor(za0, d, 64); za1 += __shfl_xor(za1, d, 64);
            zb0 += __shfl_xor(zb0, d, 64); zb1 += __shfl_xor(zb1, d, 64);
            zc0 += __shfl_xor(zc0, d, 64); zc1 += __shfl_xor(zc1, d, 64);
            zd0 += __shfl_xor(zd0, d, 64); zd1 += __shfl_xor(zd1, d, 64);
        }
        if (cg == 0) {
            if (r0g < n) {
                float mx = fmaxf(l00, l10);
                float e0 = __expf(l00 - mx), e1 = __expf(l10 - mx);
                float inv = 1.0f / (e0 + e1);
                float s0 = e0 * inv, s1 = e1 * inv;
                float2 ypv = yp[r0g];
                float y0v = s0 * (za0 + vs[0]) + s1 * (zb0 + vs[2]) + ypv.x + bcs[0];
                float y1v = s0 * (za1 + vs[1]) + s1 * (zb1 + vs[3]) + ypv.y + bcs[1];
                *(float2*)&y[(size_t)r0g * 2] = make_float2(y0v, y1v);
            }
            if (r1g < n) {
                float mx = fmaxf(l01, l11);
                float e0 = __expf(l01 - mx), e1 = __expf(l11 - mx);
                float inv = 1.0f / (e0 + e1);
                float s0 = e0 * inv, s1 = e1 * inv;
                float2 ypv = yp[r1g];
                float y0v = s0 * (zc0 + vs[0]) + s1 * (zd0 + vs[2]) + ypv.x + bcs[0];
                float y1v = s0 * (zc1 + vs[1]) + s1 * (zd1 + vs[3]) + ypv.y + bcs[1];
                *(float2*)&y[(size_t)r1g * 2] = make_float2(y0v, y1v);
            }
        }
        __syncthreads();
    }
}

extern "C" void kernel_launch(void* const* d_in, const int* in_sizes, int n_in,
                              void* d_out, int out_size, void* d_ws, size_t ws_size,
                              hipStream_t stream)
{
    const float* x    = (const float*)d_in[0];
    const int*   ei   = (const int*)d_in[1];
    const float* w1   = (const float*)d_in[2];
    const float* b1   = (const float*)d_in[3];
    const float* w2   = (const float*)d_in[4];
    const float* b2   = (const float*)d_in[5];
    const float* w3   = (const float*)d_in[6];
    const float* b3   = (const float*)d_in[7];
    const float* wg1  = (const float*)d_in[8];
    const float* bg1  = (const float*)d_in[9];
    const float* wg2  = (const float*)d_in[10];
    const float* bg2  = (const float*)d_in[11];
    const float* beta = (const float*)d_in[12];
    const float* wf   = (const float*)d_in[13];
    const float* bf   = (const float*)d_in[14];
    const float* wx   = (const float*)d_in[15];
    const float* bx   = (const float*)d_in[16];
    const float* wc   = (const float*)d_in[17];
    const float* bc   = (const float*)d_in[18];
    float* y = (float*)d_out;

    int n = in_sizes[0] / 64;     // 100000
    int e = in_sizes[1] / 2;      // 1600000
    const int* row = ei;
    const int* col = ei + e;

    // workspace ~34MB
    char* p = (char*)d_ws;
    auto alloc = [&](size_t bytes) { char* q = p; p += (bytes + 255) & ~(size_t)255; return q; };
    float*  h    = (float*)alloc((size_t)n * 64 * 4);    // 25.6MB (pairs -> h -> xp)
    int*    csr  = (int*)alloc((size_t)e * 4);           // 6.4MB
    float2* nrm2 = (float2*)alloc((size_t)n * 8);        // 0.8MB
    int*    arr  = (int*)alloc((size_t)(n + 1) * 4);     // 0.4MB
    float2* yp   = (float2*)alloc((size_t)n * 8);        // 0.8MB
    float*  pre  = (float*)alloc(8704 * 4);              // combined weights
    int*    bhist = (int*)alloc(256 * 4);
    int*    bbase = (int*)alloc(256 * 4);
    int*    bcur  = (int*)alloc(256 * 4);

    // pairs buffer (12.8MB) aliases h: consumed by k_fill3 before k_mlp writes h.
    int2* pairs = (int2*)h;
    // agg reuses x's buffer (x dead after k_mlp; harness restores d_in).
    float* agg = (float*)d_in[0];

    int ntiles_e = (n + 31) / 32;          // 3125 epi tiles
    int nbk = (n + 511) >> 9;              // 196 buckets (col>>9)
    int nsct = (e + SCT - 1) / SCT;        // 196 scatter tiles

    k_pre<<<1, 256, 0, stream>>>(wg1, bg1, wg2, bg2, wf, bf, wc, pre);
    k_zero<<<1, 256, 0, stream>>>(bhist, 256);
    k_bhist<<<nsct, 256, 0, stream>>>(col, bhist, e);
    k_bscan<<<1, 256, 0, stream>>>(bhist, bbase, bcur);
    k_bscatter2<<<nsct, 256, 0, stream>>>(row, col, bcur, pairs, e, nbk);
    k_fill3<<<nbk, 256, 0, stream>>>(pairs, bbase, bhist, arr, csr, n);
    k_mlp<<<800, 256, 0, stream>>>(x, w1, b1, w2, b2, w3, b3, arr, h, nrm2, n);
    k_gather<<<(n + 3) / 4, 256, 0, stream>>>(h, arr, csr, nrm2, beta, wc, agg, yp, n);
    k_xp<<<800, 256, 0, stream>>>(h, wx, bx, n);
    k_epi<<<1024, 256, 0, stream>>>(agg, h, yp, pre, bc, y, n, ntiles_e);
}

// Round 14
// 457.153 us; speedup vs baseline: 2.9911x; 1.0917x over previous
//
#include <hip/hip_runtime.h>
#include <math.h>

// N=100000 nodes, E=1600000 edges, HID=64, C=2, fp32.
// Hard-won constraints (R2-R13):
//  * FULLY-unrolled global-weight loads -> VGPR hoist -> spill (R2/R3).
//    #pragma unroll 2 bounds in-flight loads; weights are L1-resident.
//  * 512-thread blocks unusable (VGPR cap 128 -> spill). 256 threads only.
//  * Random 4B scatter = 64B-line write amplification; fixed by LDS-staged
//    bucket sort (R13: CSR build ~50us, WRITE back to real size).
//  * k_epi: combined-weight form (R10) + fast_tanh (R12).
//  * k_mlp was LDS-pipe-bound (R13: 2/3 of LDS instr were weight reads).
// R14: (1) k_mlp streams weights from global/L1 (gemm_core_gw, unroll 2) ->
// LDS instr/core 96->32, LDS 18KB, occupancy up. (2) k_xp fused into k_epi
// (xp computed into registers from an H tile, R8 pattern) -> 51MB round-trip
// and one launch deleted.

#define SCT 8192   // edges per scatter tile

__device__ __forceinline__ float fast_tanh(float x) {
    x = fminf(fmaxf(x, -15.f), 15.f);
    float e = __expf(2.f * x);
    return (e - 1.f) * __frcp_rn(e + 1.f);
}

__device__ __forceinline__ void fma4(float (&acc)[4], float a, const float4& w) {
    acc[0] = fmaf(a, w.x, acc[0]);
    acc[1] = fmaf(a, w.y, acc[1]);
    acc[2] = fmaf(a, w.z, acc[2]);
    acc[3] = fmaf(a, w.w, acc[3]);
}

// 256 threads: stage 32 rows x 64 cols (8 floats/thread)
__device__ __forceinline__ void load_rows32(const float* __restrict__ src, int row0, int n,
                                            float (*dst)[68], int t)
{
    int e = t * 8;
    int r = e >> 6, i = e & 63;
    int grow = row0 + r;
    float4 v0 = make_float4(0.f, 0.f, 0.f, 0.f), v1 = v0;
    if (grow < n) {
        const float* p = src + (size_t)grow * 64 + i;
        v0 = *(const float4*)p;
        v1 = *(const float4*)(p + 4);
    }
    *(float4*)&dst[r][i]     = v0;
    *(float4*)&dst[r][i + 4] = v1;
}

// ---- option A core, weights from LDS ----
__device__ __forceinline__ void gemm_core(const float (*in)[68], const float* w,
                                          const float* b, int rg, int cg,
                                          float (&acc0)[4], float (&acc1)[4])
{
#pragma unroll
    for (int dc = 0; dc < 4; dc++) { float bb = b[4*cg + dc]; acc0[dc] = bb; acc1[dc] = bb; }
    const int r0 = 2 * rg, r1 = 2 * rg + 1;
#pragma unroll
    for (int i = 0; i < 64; i += 4) {
        float4 a0 = *(const float4*)&in[r0][i];
        float4 a1 = *(const float4*)&in[r1][i];
        float4 q0 = *(const float4*)&w[(i + 0) * 64 + 4 * cg];
        float4 q1 = *(const float4*)&w[(i + 1) * 64 + 4 * cg];
        float4 q2 = *(const float4*)&w[(i + 2) * 64 + 4 * cg];
        float4 q3 = *(const float4*)&w[(i + 3) * 64 + 4 * cg];
        fma4(acc0, a0.x, q0); fma4(acc0, a0.y, q1); fma4(acc0, a0.z, q2); fma4(acc0, a0.w, q3);
        fma4(acc1, a1.x, q0); fma4(acc1, a1.y, q1); fma4(acc1, a1.z, q2); fma4(acc1, a1.w, q3);
    }
}

// ---- option A core, weights streamed from GLOBAL (L1-resident 16KB).
// unroll 2 bounds in-flight loads to 8 (full unroll = R2/R3 hoist spill). ----
__device__ __forceinline__ void gemm_core_gw(const float (*in)[68], const float* __restrict__ w,
                                             const float* b, int rg, int cg,
                                             float (&acc0)[4], float (&acc1)[4])
{
#pragma unroll
    for (int dc = 0; dc < 4; dc++) { float bb = b[4*cg + dc]; acc0[dc] = bb; acc1[dc] = bb; }
    const int r0 = 2 * rg, r1 = 2 * rg + 1;
    const float* wp = w + 4 * cg;
#pragma unroll 2
    for (int i = 0; i < 64; i += 4) {
        float4 a0 = *(const float4*)&in[r0][i];
        float4 a1 = *(const float4*)&in[r1][i];
        float4 q0 = *(const float4*)&wp[(size_t)(i + 0) * 64];
        float4 q1 = *(const float4*)&wp[(size_t)(i + 1) * 64];
        float4 q2 = *(const float4*)&wp[(size_t)(i + 2) * 64];
        float4 q3 = *(const float4*)&wp[(size_t)(i + 3) * 64];
        fma4(acc0, a0.x, q0); fma4(acc0, a0.y, q1); fma4(acc0, a0.z, q2); fma4(acc0, a0.w, q3);
        fma4(acc1, a1.x, q0); fma4(acc1, a1.y, q1); fma4(acc1, a1.z, q2); fma4(acc1, a1.w, q3);
    }
}

template <int MODE>  // 0=none, 1=relu (weights from global, writes LDS tile)
__device__ __forceinline__ void gemm_gw_lds(const float (*in)[68], const float* __restrict__ w,
                                            const float* b, float (*out)[68],
                                            int rg, int cg)
{
    float a0[4], a1[4];
    gemm_core_gw(in, w, b, rg, cg, a0, a1);
#pragma unroll
    for (int dc = 0; dc < 4; dc++) {
        float v0 = a0[dc], v1 = a1[dc];
        if (MODE == 1) { v0 = fmaxf(v0, 0.f); v1 = fmaxf(v1, 0.f); }
        a0[dc] = v0; a1[dc] = v1;
    }
    *(float4*)&out[2 * rg][4 * cg]     = make_float4(a0[0], a0[1], a0[2], a0[3]);
    *(float4*)&out[2 * rg + 1][4 * cg] = make_float4(a1[0], a1[1], a1[2], a1[3]);
}

// ---------------- CSR build: LDS-staged bucket sort (R13) ----------------

__global__ __launch_bounds__(256) void k_zero(int* __restrict__ arr, int n1)
{
    int i = blockIdx.x * 256 + threadIdx.x;
    if (i < n1) arr[i] = 0;
}

__global__ __launch_bounds__(256) void k_bhist(const int* __restrict__ col,
                                               int* __restrict__ bhist, int e)
{
    __shared__ int hist[256];
    int t = threadIdx.x;
    hist[t] = 0;
    __syncthreads();
    int base = blockIdx.x * SCT;
    int end = min(e, base + SCT);
    for (int i = base + t; i < end; i += 256)
        atomicAdd(&hist[col[i] >> 9], 1);
    __syncthreads();
    if (hist[t]) atomicAdd(&bhist[t], hist[t]);
}

__global__ __launch_bounds__(256) void k_bscan(const int* __restrict__ bhist,
                                               int* __restrict__ bbase, int* __restrict__ bcur)
{
    __shared__ int s[256];
    int t = threadIdx.x;
    int v = bhist[t];
    s[t] = v;
    __syncthreads();
    for (int d = 1; d < 256; d <<= 1) {
        int u = (t >= d) ? s[t - d] : 0;
        __syncthreads();
        s[t] += u;
        __syncthreads();
    }
    int b = s[t] - v;
    bbase[t] = b;
    bcur[t] = b;
}

__global__ __launch_bounds__(256) void k_bscatter2(const int* __restrict__ row,
    const int* __restrict__ col, int* __restrict__ bcur,
    int2* __restrict__ pairs, int e, int nbk)
{
    __shared__ int hist[256], lcur[256], gb[256], s[256];
    __shared__ int2 buf[SCT];
    int t = threadIdx.x;
    int base = blockIdx.x * SCT;
    int end = min(e, base + SCT);
    hist[t] = 0;
    __syncthreads();
    for (int i = base + t; i < end; i += 256)
        atomicAdd(&hist[col[i] >> 9], 1);
    __syncthreads();
    int v = hist[t];
    s[t] = v;
    __syncthreads();
    for (int d = 1; d < 256; d <<= 1) {
        int u = (t >= d) ? s[t - d] : 0;
        __syncthreads();
        s[t] += u;
        __syncthreads();
    }
    lcur[t] = s[t] - v;
    __syncthreads();
    for (int i = base + t; i < end; i += 256) {
        int c = col[i];
        int slot = atomicAdd(&lcur[c >> 9], 1);
        buf[slot] = make_int2(row[i], c);
    }
    if (v > 0) gb[t] = atomicAdd(&bcur[t], v);
    __syncthreads();
    for (int b = 0; b < nbk; b++) {
        int cnt = hist[b];
        if (cnt == 0) continue;
        int lo = s[b] - cnt;
        int go = gb[b];
        for (int j = t; j < cnt; j += 256)
            pairs[go + j] = buf[lo + j];
    }
}

__global__ __launch_bounds__(256) void k_fill3(const int2* __restrict__ pairs,
    const int* __restrict__ bbase, const int* __restrict__ bhist,
    int* __restrict__ arr, int* __restrict__ csr, int n)
{
    __shared__ int nh[512], nc[512], s[256];
    int b = blockIdx.x, t = threadIdx.x;
    int pbase = bbase[b];
    int cnt = bhist[b];
    int nodebase = b << 9;
    nh[t] = 0; nh[t + 256] = 0;
    __syncthreads();
    for (int i = t; i < cnt; i += 256)
        atomicAdd(&nh[pairs[pbase + i].y - nodebase], 1);
    __syncthreads();
    int v0 = nh[2 * t], v1 = nh[2 * t + 1];
    int sum = v0 + v1;
    s[t] = sum;
    __syncthreads();
    for (int d = 1; d < 256; d <<= 1) {
        int u = (t >= d) ? s[t - d] : 0;
        __syncthreads();
        s[t] += u;
        __syncthreads();
    }
    int excl = s[t] - sum;
    int n0 = nodebase + 2 * t, n1 = n0 + 1;
    nc[2 * t]     = pbase + excl;
    nc[2 * t + 1] = pbase + excl + v0;
    if (n0 < n) arr[n0] = pbase + excl + v0;
    if (n1 < n) arr[n1] = pbase + excl + v0 + v1;
    __syncthreads();
    for (int i = t; i < cnt; i += 256) {
        int2 pr = pairs[pbase + i];
        int p = atomicAdd(&nc[pr.y - nodebase], 1);
        csr[p] = pr.x;
    }
}

// ---------------- weight precombination ----------------
// pre layout (floats): W0[4096] | W1[4096] | c0[64]@8192 | c1[64]@8256 |
//                      u0[128]@8320 | u1[128]@8448 | v[4]@8576

__global__ __launch_bounds__(256) void k_pre(
    const float* __restrict__ wg1, const float* __restrict__ bg1,
    const float* __restrict__ wg2, const float* __restrict__ bg2,
    const float* __restrict__ wf,  const float* __restrict__ bf,
    const float* __restrict__ wc,  float* __restrict__ pre)
{
    __shared__ float wfs[4096];
    __shared__ float wcs[128];
    int t = threadIdx.x;
    for (int i = t; i < 4096; i += 256) wfs[i] = wf[i];
    if (t < 128) wcs[t] = wc[t];
    __syncthreads();
    int i = t & 63, jb = (t >> 6) * 16;
    float acc0[16], acc1[16];
#pragma unroll
    for (int j = 0; j < 16; j++) { acc0[j] = 0.f; acc1[j] = 0.f; }
#pragma unroll 1
    for (int k = 0; k < 64; k++) {
        float a = wg1[i * 64 + k];
        float b = wg2[i * 64 + k];
#pragma unroll
        for (int j = 0; j < 16; j++) {
            float w = wfs[k * 64 + jb + j];
            acc0[j] = fmaf(a, w, acc0[j]);
            acc1[j] = fmaf(b, w, acc1[j]);
        }
    }
#pragma unroll
    for (int j = 0; j < 16; j++) {
        pre[i * 64 + jb + j]        = acc0[j];
        pre[4096 + i * 64 + jb + j] = acc1[j];
    }
    if (t < 64) {
        float s0 = bf[t], s1 = bf[t];
#pragma unroll 1
        for (int m = 0; m < 64; m++) {
            s0 = fmaf(bg1[m], wfs[m * 64 + t], s0);
            s1 = fmaf(bg2[m], wfs[m * 64 + t], s1);
        }
        pre[8192 + t] = s0;
        pre[8256 + t] = s1;
        float u00 = 0.f, u01 = 0.f, u10 = 0.f, u11 = 0.f;
#pragma unroll 1
        for (int m = 0; m < 64; m++) {
            float g1 = wg1[t * 64 + m], g2 = wg2[t * 64 + m];
            u00 = fmaf(g1, wcs[m * 2 + 0], u00);
            u01 = fmaf(g1, wcs[m * 2 + 1], u01);
            u10 = fmaf(g2, wcs[m * 2 + 0], u10);
            u11 = fmaf(g2, wcs[m * 2 + 1], u11);
        }
        pre[8320 + t * 2]     = u00;
        pre[8320 + t * 2 + 1] = u01;
        pre[8448 + t * 2]     = u10;
        pre[8448 + t * 2 + 1] = u11;
    }
    if (t == 0) {
        float v00 = 0.f, v01 = 0.f, v10 = 0.f, v11 = 0.f;
#pragma unroll 1
        for (int m = 0; m < 64; m++) {
            v00 = fmaf(bg1[m], wcs[m * 2 + 0], v00);
            v01 = fmaf(bg1[m], wcs[m * 2 + 1], v01);
            v10 = fmaf(bg2[m], wcs[m * 2 + 0], v10);
            v11 = fmaf(bg2[m], wcs[m * 2 + 1], v11);
        }
        pre[8576] = v00; pre[8577] = v01; pre[8578] = v10; pre[8579] = v11;
    }
}

// ---------------- node MLP (weights from global/L1) + fused per-node scalars ----------------

__global__ __launch_bounds__(256) void k_mlp(const float* __restrict__ x,
    const float* __restrict__ w1, const float* __restrict__ b1,
    const float* __restrict__ w2, const float* __restrict__ b2,
    const float* __restrict__ w3, const float* __restrict__ b3,
    const int* __restrict__ arr, float* __restrict__ h,
    float2* __restrict__ nrm2, int n)
{
    __shared__ float b1s[64], b2s[64], b3s[64];
    __shared__ float xs[32][68], hs[32][68];
    int t = threadIdx.x;
    if (t < 64) { b1s[t] = b1[t]; b2s[t] = b2[t]; b3s[t] = b3[t]; }
    __syncthreads();
    int cg = t & 15, rg = t >> 4;
    for (int row0 = blockIdx.x * 32; row0 < n; row0 += gridDim.x * 32) {
        load_rows32(x, row0, n, xs, t);
        __syncthreads();
        gemm_gw_lds<1>(xs, w1, b1s, hs, rg, cg);
        __syncthreads();
        gemm_gw_lds<1>(hs, w2, b2s, xs, rg, cg);
        __syncthreads();
        {
            float a0[4], a1[4];
            gemm_core_gw(xs, w3, b3s, rg, cg, a0, a1);
            int r0 = row0 + 2 * rg, r1 = r0 + 1;
            if (r0 < n) *(float4*)&h[(size_t)r0 * 64 + 4 * cg] = make_float4(a0[0], a0[1], a0[2], a0[3]);
            if (r1 < n) *(float4*)&h[(size_t)r1 * 64 + 4 * cg] = make_float4(a1[0], a1[1], a1[2], a1[3]);
            float s0 = a0[0]*a0[0] + a0[1]*a0[1] + a0[2]*a0[2] + a0[3]*a0[3];
            float s1 = a1[0]*a1[0] + a1[1]*a1[1] + a1[2]*a1[2] + a1[3]*a1[3];
#pragma unroll
            for (int d = 1; d < 16; d <<= 1) { s0 += __shfl_xor(s0, d, 64); s1 += __shfl_xor(s1, d, 64); }
            if (cg == 0) {
                if (r0 < n) {
                    int st = (r0 == 0) ? 0 : arr[r0 - 1];
                    nrm2[r0] = make_float2(1.0f / (sqrtf(s0) + 1e-12f),
                                           rsqrtf((float)(arr[r0] - st + 1)));
                }
                if (r1 < n) {
                    int st = arr[r1 - 1];
                    nrm2[r1] = make_float2(1.0f / (sqrtf(s1) + 1e-12f),
                                           rsqrtf((float)(arr[r1] - st + 1)));
                }
            }
        }
        __syncthreads();
    }
}

// ---------------- edge pass: wave/node, 8 edge-groups x 8 lanes ----------------

__global__ __launch_bounds__(256) void k_gather(const float* __restrict__ h,
    const int* __restrict__ arr, const int* __restrict__ csr,
    const float2* __restrict__ nrm2, const float* __restrict__ beta_p,
    const float* __restrict__ wc,
    float* __restrict__ agg, float2* __restrict__ yp, int n)
{
    int node = blockIdx.x * 4 + (threadIdx.x >> 6);
    if (node >= n) return;
    int lane = threadIdx.x & 63;
    int g = lane >> 3, s = lane & 7;
    float beta = beta_p[0];
    const float4* hrow = (const float4*)(h + (size_t)node * 64);
    float4 hcA = hrow[2 * s];
    float4 hcB = hrow[2 * s + 1];
    float ss = hcA.x*hcA.x + hcA.y*hcA.y + hcA.z*hcA.z + hcA.w*hcA.w
             + hcB.x*hcB.x + hcB.y*hcB.y + hcB.z*hcB.z + hcB.w*hcB.w;
#pragma unroll
    for (int d = 1; d < 8; d <<= 1) ss += __shfl_xor(ss, d, 64);
    float2 nc = nrm2[node];
    float rnc = nc.x, dc = nc.y;
    float wself = __expf(beta * ss * rnc * rnc);
    float4 aA = make_float4(0.f,0.f,0.f,0.f), aB = aA, nA = aA, nB = aA;
    float denom = 0.f;
    if (g == 0) {
        aA = make_float4(dc*hcA.x, dc*hcA.y, dc*hcA.z, dc*hcA.w);
        aB = make_float4(dc*hcB.x, dc*hcB.y, dc*hcB.z, dc*hcB.w);
        nA = make_float4(wself*hcA.x, wself*hcA.y, wself*hcA.z, wself*hcA.w);
        nB = make_float4(wself*hcB.x, wself*hcB.y, wself*hcB.z, wself*hcB.w);
        denom = wself;
    }
    int start = (node == 0) ? 0 : arr[node - 1];
    int end = arr[node];
#pragma unroll 1
    for (int k0 = start; k0 < end; k0 += 64) {
        int m = min(64, end - k0);
        int idx = 0; float rv = 0.f, dv = 0.f;
        if (lane < m) {
            idx = csr[k0 + lane];
            float2 nd = nrm2[idx];
            rv = nd.x; dv = nd.y;
        }
        int ei = __shfl(idx, g, 64);
        const float4* rp = (const float4*)(h + (size_t)ei * 64);
        float4 cA = rp[2 * s], cB = rp[2 * s + 1];
#pragma unroll 1
        for (int k = 0; k < m; k += 8) {
            float4 hA = cA, hB = cB;
            if (k + 8 < m) {
                int e2 = __shfl(idx, k + 8 + g, 64);
                const float4* p2 = (const float4*)(h + (size_t)e2 * 64);
                cA = p2[2 * s]; cB = p2[2 * s + 1];
            }
            float rnr = __shfl(rv, k + g, 64);
            float dvr = __shfl(dv, k + g, 64);
            float p = hA.x*hcA.x + hA.y*hcA.y + hA.z*hcA.z + hA.w*hcA.w
                    + hB.x*hcB.x + hB.y*hcB.y + hB.z*hcB.z + hB.w*hcB.w;
#pragma unroll
            for (int d = 1; d < 8; d <<= 1) p += __shfl_xor(p, d, 64);
            bool act = (k + g) < m;
            float w   = act ? __expf(beta * p * rnc * rnr) : 0.f;
            float dve = act ? dvr : 0.f;
            aA.x = fmaf(dve, hA.x, aA.x); aA.y = fmaf(dve, hA.y, aA.y);
            aA.z = fmaf(dve, hA.z, aA.z); aA.w = fmaf(dve, hA.w, aA.w);
            aB.x = fmaf(dve, hB.x, aB.x); aB.y = fmaf(dve, hB.y, aB.y);
            aB.z = fmaf(dve, hB.z, aB.z); aB.w = fmaf(dve, hB.w, aB.w);
            nA.x = fmaf(w, hA.x, nA.x); nA.y = fmaf(w, hA.y, nA.y);
            nA.z = fmaf(w, hA.z, nA.z); nA.w = fmaf(w, hA.w, nA.w);
            nB.x = fmaf(w, hB.x, nB.x); nB.y = fmaf(w, hB.y, nB.y);
            nB.z = fmaf(w, hB.z, nB.z); nB.w = fmaf(w, hB.w, nB.w);
            denom += w;
        }
    }
#pragma unroll
    for (int d = 8; d < 64; d <<= 1) {
        aA.x += __shfl_xor(aA.x, d, 64); aA.y += __shfl_xor(aA.y, d, 64);
        aA.z += __shfl_xor(aA.z, d, 64); aA.w += __shfl_xor(aA.w, d, 64);
        aB.x += __shfl_xor(aB.x, d, 64); aB.y += __shfl_xor(aB.y, d, 64);
        aB.z += __shfl_xor(aB.z, d, 64); aB.w += __shfl_xor(aB.w, d, 64);
        nA.x += __shfl_xor(nA.x, d, 64); nA.y += __shfl_xor(nA.y, d, 64);
        nA.z += __shfl_xor(nA.z, d, 64); nA.w += __shfl_xor(nA.w, d, 64);
        nB.x += __shfl_xor(nB.x, d, 64); nB.y += __shfl_xor(nB.y, d, 64);
        nB.z += __shfl_xor(nB.z, d, 64); nB.w += __shfl_xor(nB.w, d, 64);
        denom += __shfl_xor(denom, d, 64);
    }
    if (g == 0) {
        float4* op = (float4*)(agg + (size_t)node * 64);
        op[2 * s]     = make_float4(dc*aA.x, dc*aA.y, dc*aA.z, dc*aA.w);
        op[2 * s + 1] = make_float4(dc*aB.x, dc*aB.y, dc*aB.z, dc*aB.w);
    }
    float inv = 1.0f / denom;
    float cx = 0.f, cy = 0.f;
#pragma unroll
    for (int j = 0; j < 4; j++) {
        float2 wa = ((const float2*)wc)[64 + 8 * s + j];
        float2 wb = ((const float2*)wc)[64 + 8 * s + 4 + j];
        float va = (&nA.x)[j], vb = (&nB.x)[j];
        cx = fmaf(va, wa.x, cx); cx = fmaf(vb, wb.x, cx);
        cy = fmaf(va, wa.y, cy); cy = fmaf(vb, wb.y, cy);
    }
    cx *= inv; cy *= inv;
#pragma unroll
    for (int d = 1; d < 8; d <<= 1) { cx += __shfl_xor(cx, d, 64); cy += __shfl_xor(cy, d, 64); }
    if (lane == 0) yp[node] = make_float2(cx, cy);
}

// ---------------- epilogue: xp fused (H tile + wxs), combined weights ----------------
// xp = fast_tanh(H@wx+bx) in registers (R8 pattern); then
// l_k[row] = sum_j fast_tanh((agg@W_k + c_k)[row][j]) * xp[row][j]
// z_k[row][c] = (agg . u_k[:,c]) + v_k[c] ; y = s0*z0+s1*z1+yp+bc

__global__ __launch_bounds__(256) void k_epi(const float* __restrict__ agg,
    const float* __restrict__ hbuf, const float2* __restrict__ yp,
    const float* __restrict__ pre, const float* __restrict__ wx,
    const float* __restrict__ bx, const float* __restrict__ bc,
    float* __restrict__ y, int n, int ntiles)
{
    __shared__ float W0s[4096], W1s[4096], wxs[4096];
    __shared__ float c0s[64], c1s[64], bxs[64], us[256], vs[4], bcs[2];
    __shared__ float A[32][68], H[32][68];
    int t = threadIdx.x;
    for (int i = t; i < 4096; i += 256) { W0s[i] = pre[i]; W1s[i] = pre[4096 + i]; wxs[i] = wx[i]; }
    if (t < 64) { c0s[t] = pre[8192 + t]; c1s[t] = pre[8256 + t]; bxs[t] = bx[t]; }
    us[t] = pre[8320 + t];
    if (t < 4) vs[t] = pre[8576 + t];
    if (t < 2) bcs[t] = bc[t];
    __syncthreads();
    int cg = t & 15, rg = t >> 4;
    for (int tile = blockIdx.x; tile < ntiles; tile += gridDim.x) {
        int row0 = tile * 32;
        load_rows32(agg,  row0, n, A, t);
        load_rows32(hbuf, row0, n, H, t);
        __syncthreads();
        int r0g = row0 + 2 * rg, r1g = r0g + 1;
        // xp in registers
        float xp0[4], xp1[4];
        gemm_core(H, wxs, bxs, rg, cg, xp0, xp1);
#pragma unroll
        for (int j = 0; j < 4; j++) { xp0[j] = fast_tanh(xp0[j]); xp1[j] = fast_tanh(xp1[j]); }
        float a0[4], a1[4];
        gemm_core(A, W0s, c0s, rg, cg, a0, a1);
        float l00 = 0.f, l01 = 0.f;
#pragma unroll
        for (int j = 0; j < 4; j++) {
            l00 = fmaf(fast_tanh(a0[j]), xp0[j], l00);
            l01 = fmaf(fast_tanh(a1[j]), xp1[j], l01);
        }
        gemm_core(A, W1s, c1s, rg, cg, a0, a1);
        float l10 = 0.f, l11 = 0.f;
#pragma unroll
        for (int j = 0; j < 4; j++) {
            l10 = fmaf(fast_tanh(a0[j]), xp0[j], l10);
            l11 = fmaf(fast_tanh(a1[j]), xp1[j], l11);
        }
        float4 av0 = *(const float4*)&A[2 * rg][4 * cg];
        float4 av1 = *(const float4*)&A[2 * rg + 1][4 * cg];
        float za0=0.f, za1=0.f, zb0=0.f, zb1=0.f;
        float zc0=0.f, zc1=0.f, zd0=0.f, zd1=0.f;
#pragma unroll
        for (int j = 0; j < 4; j++) {
            int k = 4 * cg + j;
            float u0c0 = us[k * 2], u0c1 = us[k * 2 + 1];
            float u1c0 = us[128 + k * 2], u1c1 = us[128 + k * 2 + 1];
            float p0 = (&av0.x)[j], p1 = (&av1.x)[j];
            za0 = fmaf(p0, u0c0, za0); za1 = fmaf(p0, u0c1, za1);
            zb0 = fmaf(p0, u1c0, zb0); zb1 = fmaf(p0, u1c1, zb1);
            zc0 = fmaf(p1, u0c0, zc0); zc1 = fmaf(p1, u0c1, zc1);
            zd0 = fmaf(p1, u1c0, zd0); zd1 = fmaf(p1, u1c1, zd1);
        }
#pragma unroll
        for (int d = 1; d < 16; d <<= 1) {
            l00 += __shfl_xor(l00, d, 64); l01 += __shfl_xor(l01, d, 64);
            l10 += __shfl_xor(l10, d, 64); l11 += __shfl_xor(l11, d, 64);
            za0 += __shfl_xor(za0, d, 64); za1 += __shfl_xor(za1, d, 64);
            zb0 += __shfl_xor(zb0, d, 64); zb1 += __shfl_xor(zb1, d, 64);
            zc0 += __shfl_xor(zc0, d, 64); zc1 += __shfl_xor(zc1, d, 64);
            zd0 += __shfl_xor(zd0, d, 64); zd1 += __shfl_xor(zd1, d, 64);
        }
        if (cg == 0) {
            if (r0g < n) {
                float mx = fmaxf(l00, l10);
                float e0 = __expf(l00 - mx), e1 = __expf(l10 - mx);
                float inv = 1.0f / (e0 + e1);
                float s0 = e0 * inv, s1 = e1 * inv;
                float2 ypv = yp[r0g];
                float y0v = s0 * (za0 + vs[0]) + s1 * (zb0 + vs[2]) + ypv.x + bcs[0];
                float y1v = s0 * (za1 + vs[1]) + s1 * (zb1 + vs[3]) + ypv.y + bcs[1];
                *(float2*)&y[(size_t)r0g * 2] = make_float2(y0v, y1v);
            }
            if (r1g < n) {
                float mx = fmaxf(l01, l11);
                float e0 = __expf(l01 - mx), e1 = __expf(l11 - mx);
                float inv = 1.0f / (e0 + e1);
                float s0 = e0 * inv, s1 = e1 * inv;
                float2 ypv = yp[r1g];
                float y0v = s0 * (zc0 + vs[0]) + s1 * (zd0 + vs[2]) + ypv.x + bcs[0];
                float y1v = s0 * (zc1 + vs[1]) + s1 * (zd1 + vs[3]) + ypv.y + bcs[1];
                *(float2*)&y[(size_t)r1g * 2] = make_float2(y0v, y1v);
            }
        }
        __syncthreads();
    }
}

extern "C" void kernel_launch(void* const* d_in, const int* in_sizes, int n_in,
                              void* d_out, int out_size, void* d_ws, size_t ws_size,
                              hipStream_t stream)
{
    const float* x    = (const float*)d_in[0];
    const int*   ei   = (const int*)d_in[1];
    const float* w1   = (const float*)d_in[2];
    const float* b1   = (const float*)d_in[3];
    const float* w2   = (const float*)d_in[4];
    const float* b2   = (const float*)d_in[5];
    const float* w3   = (const float*)d_in[6];
    const float* b3   = (const float*)d_in[7];
    const float* wg1  = (const float*)d_in[8];
    const float* bg1  = (const float*)d_in[9];
    const float* wg2  = (const float*)d_in[10];
    const float* bg2  = (const float*)d_in[11];
    const float* beta = (const float*)d_in[12];
    const float* wf   = (const float*)d_in[13];
    const float* bf   = (const float*)d_in[14];
    const float* wx   = (const float*)d_in[15];
    const float* bx   = (const float*)d_in[16];
    const float* wc   = (const float*)d_in[17];
    const float* bc   = (const float*)d_in[18];
    float* y = (float*)d_out;

    int n = in_sizes[0] / 64;     // 100000
    int e = in_sizes[1] / 2;      // 1600000
    const int* row = ei;
    const int* col = ei + e;

    // workspace ~34MB
    char* p = (char*)d_ws;
    auto alloc = [&](size_t bytes) { char* q = p; p += (bytes + 255) & ~(size_t)255; return q; };
    float*  h    = (float*)alloc((size_t)n * 64 * 4);    // 25.6MB (pairs -> h)
    int*    csr  = (int*)alloc((size_t)e * 4);           // 6.4MB
    float2* nrm2 = (float2*)alloc((size_t)n * 8);        // 0.8MB
    int*    arr  = (int*)alloc((size_t)(n + 1) * 4);     // 0.4MB
    float2* yp   = (float2*)alloc((size_t)n * 8);        // 0.8MB
    float*  pre  = (float*)alloc(8704 * 4);              // combined weights
    int*    bhist = (int*)alloc(256 * 4);
    int*    bbase = (int*)alloc(256 * 4);
    int*    bcur  = (int*)alloc(256 * 4);

    // pairs buffer (12.8MB) aliases h: consumed by k_fill3 before k_mlp writes h.
    int2* pairs = (int2*)h;
    // agg reuses x's buffer (x dead after k_mlp; harness restores d_in).
    float* agg = (float*)d_in[0];

    int ntiles_e = (n + 31) / 32;          // 3125 epi tiles
    int nbk = (n + 511) >> 9;              // 196 buckets (col>>9)
    int nsct = (e + SCT - 1) / SCT;        // 196 scatter tiles

    k_pre<<<1, 256, 0, stream>>>(wg1, bg1, wg2, bg2, wf, bf, wc, pre);
    k_zero<<<1, 256, 0, stream>>>(bhist, 256);
    k_bhist<<<nsct, 256, 0, stream>>>(col, bhist, e);
    k_bscan<<<1, 256, 0, stream>>>(bhist, bbase, bcur);
    k_bscatter2<<<nsct, 256, 0, stream>>>(row, col, bcur, pairs, e, nbk);
    k_fill3<<<nbk, 256, 0, stream>>>(pairs, bbase, bhist, arr, csr, n);
    k_mlp<<<800, 256, 0, stream>>>(x, w1, b1, w2, b2, w3, b3, arr, h, nrm2, n);
    k_gather<<<(n + 3) / 4, 256, 0, stream>>>(h, arr, csr, nrm2, beta, wc, agg, yp, n);
    k_epi<<<1024, 256, 0, stream>>>(agg, h, yp, pre, wx, bx, bc, y, n, ntiles_e);
}

// Round 15
// 446.316 us; speedup vs baseline: 3.0638x; 1.0243x over previous
//
#include <hip/hip_runtime.h>
#include <math.h>

// N=100000 nodes, E=1600000 edges, HID=64, C=2, fp32.
// Hard-won constraints (R2-R14):
//  * FULLY-unrolled global-weight loads -> VGPR hoist -> spill (R2/R3);
//    #pragma unroll 2 bounds in-flight loads (R14: VGPR 48, no spill).
//  * 512-thread blocks unusable (VGPR cap 128 -> spill). 256 threads only.
//  * Random 4B scatter = 64B-line write amplification; fixed by LDS-staged
//    bucket sort (R13).
//  * k_epi: combined-weight form (R10) + fast_tanh (R12) + fused xp (R14).
//  * k_mlp R14: weights from global/L1 -> LDS 18KB, VGPR 48, but dur
//    unchanged at 100us: occupancy was GRID-limited (800 blocks ~ 3/CU vs
//    8/CU capacity). R15: grid 3125 (one tile/block) -> fill the machine.

#define SCT 8192   // edges per scatter tile

__device__ __forceinline__ float fast_tanh(float x) {
    x = fminf(fmaxf(x, -15.f), 15.f);
    float e = __expf(2.f * x);
    return (e - 1.f) * __frcp_rn(e + 1.f);
}

__device__ __forceinline__ void fma4(float (&acc)[4], float a, const float4& w) {
    acc[0] = fmaf(a, w.x, acc[0]);
    acc[1] = fmaf(a, w.y, acc[1]);
    acc[2] = fmaf(a, w.z, acc[2]);
    acc[3] = fmaf(a, w.w, acc[3]);
}

// 256 threads: stage 32 rows x 64 cols (8 floats/thread)
__device__ __forceinline__ void load_rows32(const float* __restrict__ src, int row0, int n,
                                            float (*dst)[68], int t)
{
    int e = t * 8;
    int r = e >> 6, i = e & 63;
    int grow = row0 + r;
    float4 v0 = make_float4(0.f, 0.f, 0.f, 0.f), v1 = v0;
    if (grow < n) {
        const float* p = src + (size_t)grow * 64 + i;
        v0 = *(const float4*)p;
        v1 = *(const float4*)(p + 4);
    }
    *(float4*)&dst[r][i]     = v0;
    *(float4*)&dst[r][i + 4] = v1;
}

// ---- option A core, weights from LDS ----
__device__ __forceinline__ void gemm_core(const float (*in)[68], const float* w,
                                          const float* b, int rg, int cg,
                                          float (&acc0)[4], float (&acc1)[4])
{
#pragma unroll
    for (int dc = 0; dc < 4; dc++) { float bb = b[4*cg + dc]; acc0[dc] = bb; acc1[dc] = bb; }
    const int r0 = 2 * rg, r1 = 2 * rg + 1;
#pragma unroll
    for (int i = 0; i < 64; i += 4) {
        float4 a0 = *(const float4*)&in[r0][i];
        float4 a1 = *(const float4*)&in[r1][i];
        float4 q0 = *(const float4*)&w[(i + 0) * 64 + 4 * cg];
        float4 q1 = *(const float4*)&w[(i + 1) * 64 + 4 * cg];
        float4 q2 = *(const float4*)&w[(i + 2) * 64 + 4 * cg];
        float4 q3 = *(const float4*)&w[(i + 3) * 64 + 4 * cg];
        fma4(acc0, a0.x, q0); fma4(acc0, a0.y, q1); fma4(acc0, a0.z, q2); fma4(acc0, a0.w, q3);
        fma4(acc1, a1.x, q0); fma4(acc1, a1.y, q1); fma4(acc1, a1.z, q2); fma4(acc1, a1.w, q3);
    }
}

// ---- option A core, weights streamed from GLOBAL (L1-resident 16KB).
// unroll 2 bounds in-flight loads (full unroll = R2/R3 hoist spill). ----
__device__ __forceinline__ void gemm_core_gw(const float (*in)[68], const float* __restrict__ w,
                                             const float* b, int rg, int cg,
                                             float (&acc0)[4], float (&acc1)[4])
{
#pragma unroll
    for (int dc = 0; dc < 4; dc++) { float bb = b[4*cg + dc]; acc0[dc] = bb; acc1[dc] = bb; }
    const int r0 = 2 * rg, r1 = 2 * rg + 1;
    const float* wp = w + 4 * cg;
#pragma unroll 2
    for (int i = 0; i < 64; i += 4) {
        float4 a0 = *(const float4*)&in[r0][i];
        float4 a1 = *(const float4*)&in[r1][i];
        float4 q0 = *(const float4*)&wp[(size_t)(i + 0) * 64];
        float4 q1 = *(const float4*)&wp[(size_t)(i + 1) * 64];
        float4 q2 = *(const float4*)&wp[(size_t)(i + 2) * 64];
        float4 q3 = *(const float4*)&wp[(size_t)(i + 3) * 64];
        fma4(acc0, a0.x, q0); fma4(acc0, a0.y, q1); fma4(acc0, a0.z, q2); fma4(acc0, a0.w, q3);
        fma4(acc1, a1.x, q0); fma4(acc1, a1.y, q1); fma4(acc1, a1.z, q2); fma4(acc1, a1.w, q3);
    }
}

template <int MODE>  // 0=none, 1=relu (weights from global, writes LDS tile)
__device__ __forceinline__ void gemm_gw_lds(const float (*in)[68], const float* __restrict__ w,
                                            const float* b, float (*out)[68],
                                            int rg, int cg)
{
    float a0[4], a1[4];
    gemm_core_gw(in, w, b, rg, cg, a0, a1);
#pragma unroll
    for (int dc = 0; dc < 4; dc++) {
        float v0 = a0[dc], v1 = a1[dc];
        if (MODE == 1) { v0 = fmaxf(v0, 0.f); v1 = fmaxf(v1, 0.f); }
        a0[dc] = v0; a1[dc] = v1;
    }
    *(float4*)&out[2 * rg][4 * cg]     = make_float4(a0[0], a0[1], a0[2], a0[3]);
    *(float4*)&out[2 * rg + 1][4 * cg] = make_float4(a1[0], a1[1], a1[2], a1[3]);
}

// ---------------- CSR build: LDS-staged bucket sort (R13) ----------------

__global__ __launch_bounds__(256) void k_zero(int* __restrict__ arr, int n1)
{
    int i = blockIdx.x * 256 + threadIdx.x;
    if (i < n1) arr[i] = 0;
}

__global__ __launch_bounds__(256) void k_bhist(const int* __restrict__ col,
                                               int* __restrict__ bhist, int e)
{
    __shared__ int hist[256];
    int t = threadIdx.x;
    hist[t] = 0;
    __syncthreads();
    int base = blockIdx.x * SCT;
    int end = min(e, base + SCT);
    for (int i = base + t; i < end; i += 256)
        atomicAdd(&hist[col[i] >> 9], 1);
    __syncthreads();
    if (hist[t]) atomicAdd(&bhist[t], hist[t]);
}

__global__ __launch_bounds__(256) void k_bscan(const int* __restrict__ bhist,
                                               int* __restrict__ bbase, int* __restrict__ bcur)
{
    __shared__ int s[256];
    int t = threadIdx.x;
    int v = bhist[t];
    s[t] = v;
    __syncthreads();
    for (int d = 1; d < 256; d <<= 1) {
        int u = (t >= d) ? s[t - d] : 0;
        __syncthreads();
        s[t] += u;
        __syncthreads();
    }
    int b = s[t] - v;
    bbase[t] = b;
    bcur[t] = b;
}

__global__ __launch_bounds__(256) void k_bscatter2(const int* __restrict__ row,
    const int* __restrict__ col, int* __restrict__ bcur,
    int2* __restrict__ pairs, int e, int nbk)
{
    __shared__ int hist[256], lcur[256], gb[256], s[256];
    __shared__ int2 buf[SCT];
    int t = threadIdx.x;
    int base = blockIdx.x * SCT;
    int end = min(e, base + SCT);
    hist[t] = 0;
    __syncthreads();
    for (int i = base + t; i < end; i += 256)
        atomicAdd(&hist[col[i] >> 9], 1);
    __syncthreads();
    int v = hist[t];
    s[t] = v;
    __syncthreads();
    for (int d = 1; d < 256; d <<= 1) {
        int u = (t >= d) ? s[t - d] : 0;
        __syncthreads();
        s[t] += u;
        __syncthreads();
    }
    lcur[t] = s[t] - v;
    __syncthreads();
    for (int i = base + t; i < end; i += 256) {
        int c = col[i];
        int slot = atomicAdd(&lcur[c >> 9], 1);
        buf[slot] = make_int2(row[i], c);
    }
    if (v > 0) gb[t] = atomicAdd(&bcur[t], v);
    __syncthreads();
    for (int b = 0; b < nbk; b++) {
        int cnt = hist[b];
        if (cnt == 0) continue;
        int lo = s[b] - cnt;
        int go = gb[b];
        for (int j = t; j < cnt; j += 256)
            pairs[go + j] = buf[lo + j];
    }
}

__global__ __launch_bounds__(256) void k_fill3(const int2* __restrict__ pairs,
    const int* __restrict__ bbase, const int* __restrict__ bhist,
    int* __restrict__ arr, int* __restrict__ csr, int n)
{
    __shared__ int nh[512], nc[512], s[256];
    int b = blockIdx.x, t = threadIdx.x;
    int pbase = bbase[b];
    int cnt = bhist[b];
    int nodebase = b << 9;
    nh[t] = 0; nh[t + 256] = 0;
    __syncthreads();
    for (int i = t; i < cnt; i += 256)
        atomicAdd(&nh[pairs[pbase + i].y - nodebase], 1);
    __syncthreads();
    int v0 = nh[2 * t], v1 = nh[2 * t + 1];
    int sum = v0 + v1;
    s[t] = sum;
    __syncthreads();
    for (int d = 1; d < 256; d <<= 1) {
        int u = (t >= d) ? s[t - d] : 0;
        __syncthreads();
        s[t] += u;
        __syncthreads();
    }
    int excl = s[t] - sum;
    int n0 = nodebase + 2 * t, n1 = n0 + 1;
    nc[2 * t]     = pbase + excl;
    nc[2 * t + 1] = pbase + excl + v0;
    if (n0 < n) arr[n0] = pbase + excl + v0;
    if (n1 < n) arr[n1] = pbase + excl + v0 + v1;
    __syncthreads();
    for (int i = t; i < cnt; i += 256) {
        int2 pr = pairs[pbase + i];
        int p = atomicAdd(&nc[pr.y - nodebase], 1);
        csr[p] = pr.x;
    }
}

// ---------------- weight precombination ----------------
// pre layout (floats): W0[4096] | W1[4096] | c0[64]@8192 | c1[64]@8256 |
//                      u0[128]@8320 | u1[128]@8448 | v[4]@8576

__global__ __launch_bounds__(256) void k_pre(
    const float* __restrict__ wg1, const float* __restrict__ bg1,
    const float* __restrict__ wg2, const float* __restrict__ bg2,
    const float* __restrict__ wf,  const float* __restrict__ bf,
    const float* __restrict__ wc,  float* __restrict__ pre)
{
    __shared__ float wfs[4096];
    __shared__ float wcs[128];
    int t = threadIdx.x;
    for (int i = t; i < 4096; i += 256) wfs[i] = wf[i];
    if (t < 128) wcs[t] = wc[t];
    __syncthreads();
    int i = t & 63, jb = (t >> 6) * 16;
    float acc0[16], acc1[16];
#pragma unroll
    for (int j = 0; j < 16; j++) { acc0[j] = 0.f; acc1[j] = 0.f; }
#pragma unroll 1
    for (int k = 0; k < 64; k++) {
        float a = wg1[i * 64 + k];
        float b = wg2[i * 64 + k];
#pragma unroll
        for (int j = 0; j < 16; j++) {
            float w = wfs[k * 64 + jb + j];
            acc0[j] = fmaf(a, w, acc0[j]);
            acc1[j] = fmaf(b, w, acc1[j]);
        }
    }
#pragma unroll
    for (int j = 0; j < 16; j++) {
        pre[i * 64 + jb + j]        = acc0[j];
        pre[4096 + i * 64 + jb + j] = acc1[j];
    }
    if (t < 64) {
        float s0 = bf[t], s1 = bf[t];
#pragma unroll 1
        for (int m = 0; m < 64; m++) {
            s0 = fmaf(bg1[m], wfs[m * 64 + t], s0);
            s1 = fmaf(bg2[m], wfs[m * 64 + t], s1);
        }
        pre[8192 + t] = s0;
        pre[8256 + t] = s1;
        float u00 = 0.f, u01 = 0.f, u10 = 0.f, u11 = 0.f;
#pragma unroll 1
        for (int m = 0; m < 64; m++) {
            float g1 = wg1[t * 64 + m], g2 = wg2[t * 64 + m];
            u00 = fmaf(g1, wcs[m * 2 + 0], u00);
            u01 = fmaf(g1, wcs[m * 2 + 1], u01);
            u10 = fmaf(g2, wcs[m * 2 + 0], u10);
            u11 = fmaf(g2, wcs[m * 2 + 1], u11);
        }
        pre[8320 + t * 2]     = u00;
        pre[8320 + t * 2 + 1] = u01;
        pre[8448 + t * 2]     = u10;
        pre[8448 + t * 2 + 1] = u11;
    }
    if (t == 0) {
        float v00 = 0.f, v01 = 0.f, v10 = 0.f, v11 = 0.f;
#pragma unroll 1
        for (int m = 0; m < 64; m++) {
            v00 = fmaf(bg1[m], wcs[m * 2 + 0], v00);
            v01 = fmaf(bg1[m], wcs[m * 2 + 1], v01);
            v10 = fmaf(bg2[m], wcs[m * 2 + 0], v10);
            v11 = fmaf(bg2[m], wcs[m * 2 + 1], v11);
        }
        pre[8576] = v00; pre[8577] = v01; pre[8578] = v10; pre[8579] = v11;
    }
}

// ---------------- node MLP (weights from global/L1) + fused per-node scalars ----------------

__global__ __launch_bounds__(256) void k_mlp(const float* __restrict__ x,
    const float* __restrict__ w1, const float* __restrict__ b1,
    const float* __restrict__ w2, const float* __restrict__ b2,
    const float* __restrict__ w3, const float* __restrict__ b3,
    const int* __restrict__ arr, float* __restrict__ h,
    float2* __restrict__ nrm2, int n)
{
    __shared__ float b1s[64], b2s[64], b3s[64];
    __shared__ float xs[32][68], hs[32][68];
    int t = threadIdx.x;
    if (t < 64) { b1s[t] = b1[t]; b2s[t] = b2[t]; b3s[t] = b3[t]; }
    __syncthreads();
    int cg = t & 15, rg = t >> 4;
    for (int row0 = blockIdx.x * 32; row0 < n; row0 += gridDim.x * 32) {
        load_rows32(x, row0, n, xs, t);
        __syncthreads();
        gemm_gw_lds<1>(xs, w1, b1s, hs, rg, cg);
        __syncthreads();
        gemm_gw_lds<1>(hs, w2, b2s, xs, rg, cg);
        __syncthreads();
        {
            float a0[4], a1[4];
            gemm_core_gw(xs, w3, b3s, rg, cg, a0, a1);
            int r0 = row0 + 2 * rg, r1 = r0 + 1;
            if (r0 < n) *(float4*)&h[(size_t)r0 * 64 + 4 * cg] = make_float4(a0[0], a0[1], a0[2], a0[3]);
            if (r1 < n) *(float4*)&h[(size_t)r1 * 64 + 4 * cg] = make_float4(a1[0], a1[1], a1[2], a1[3]);
            float s0 = a0[0]*a0[0] + a0[1]*a0[1] + a0[2]*a0[2] + a0[3]*a0[3];
            float s1 = a1[0]*a1[0] + a1[1]*a1[1] + a1[2]*a1[2] + a1[3]*a1[3];
#pragma unroll
            for (int d = 1; d < 16; d <<= 1) { s0 += __shfl_xor(s0, d, 64); s1 += __shfl_xor(s1, d, 64); }
            if (cg == 0) {
                if (r0 < n) {
                    int st = (r0 == 0) ? 0 : arr[r0 - 1];
                    nrm2[r0] = make_float2(1.0f / (sqrtf(s0) + 1e-12f),
                                           rsqrtf((float)(arr[r0] - st + 1)));
                }
                if (r1 < n) {
                    int st = arr[r1 - 1];
                    nrm2[r1] = make_float2(1.0f / (sqrtf(s1) + 1e-12f),
                                           rsqrtf((float)(arr[r1] - st + 1)));
                }
            }
        }
        __syncthreads();
    }
}

// ---------------- edge pass: wave/node, 8 edge-groups x 8 lanes ----------------

__global__ __launch_bounds__(256) void k_gather(const float* __restrict__ h,
    const int* __restrict__ arr, const int* __restrict__ csr,
    const float2* __restrict__ nrm2, const float* __restrict__ beta_p,
    const float* __restrict__ wc,
    float* __restrict__ agg, float2* __restrict__ yp, int n)
{
    int node = blockIdx.x * 4 + (threadIdx.x >> 6);
    if (node >= n) return;
    int lane = threadIdx.x & 63;
    int g = lane >> 3, s = lane & 7;
    float beta = beta_p[0];
    const float4* hrow = (const float4*)(h + (size_t)node * 64);
    float4 hcA = hrow[2 * s];
    float4 hcB = hrow[2 * s + 1];
    float ss = hcA.x*hcA.x + hcA.y*hcA.y + hcA.z*hcA.z + hcA.w*hcA.w
             + hcB.x*hcB.x + hcB.y*hcB.y + hcB.z*hcB.z + hcB.w*hcB.w;
#pragma unroll
    for (int d = 1; d < 8; d <<= 1) ss += __shfl_xor(ss, d, 64);
    float2 nc = nrm2[node];
    float rnc = nc.x, dc = nc.y;
    float wself = __expf(beta * ss * rnc * rnc);
    float4 aA = make_float4(0.f,0.f,0.f,0.f), aB = aA, nA = aA, nB = aA;
    float denom = 0.f;
    if (g == 0) {
        aA = make_float4(dc*hcA.x, dc*hcA.y, dc*hcA.z, dc*hcA.w);
        aB = make_float4(dc*hcB.x, dc*hcB.y, dc*hcB.z, dc*hcB.w);
        nA = make_float4(wself*hcA.x, wself*hcA.y, wself*hcA.z, wself*hcA.w);
        nB = make_float4(wself*hcB.x, wself*hcB.y, wself*hcB.z, wself*hcB.w);
        denom = wself;
    }
    int start = (node == 0) ? 0 : arr[node - 1];
    int end = arr[node];
#pragma unroll 1
    for (int k0 = start; k0 < end; k0 += 64) {
        int m = min(64, end - k0);
        int idx = 0; float rv = 0.f, dv = 0.f;
        if (lane < m) {
            idx = csr[k0 + lane];
            float2 nd = nrm2[idx];
            rv = nd.x; dv = nd.y;
        }
        int ei = __shfl(idx, g, 64);
        const float4* rp = (const float4*)(h + (size_t)ei * 64);
        float4 cA = rp[2 * s], cB = rp[2 * s + 1];
#pragma unroll 1
        for (int k = 0; k < m; k += 8) {
            float4 hA = cA, hB = cB;
            if (k + 8 < m) {
                int e2 = __shfl(idx, k + 8 + g, 64);
                const float4* p2 = (const float4*)(h + (size_t)e2 * 64);
                cA = p2[2 * s]; cB = p2[2 * s + 1];
            }
            float rnr = __shfl(rv, k + g, 64);
            float dvr = __shfl(dv, k + g, 64);
            float p = hA.x*hcA.x + hA.y*hcA.y + hA.z*hcA.z + hA.w*hcA.w
                    + hB.x*hcB.x + hB.y*hcB.y + hB.z*hcB.z + hB.w*hcB.w;
#pragma unroll
            for (int d = 1; d < 8; d <<= 1) p += __shfl_xor(p, d, 64);
            bool act = (k + g) < m;
            float w   = act ? __expf(beta * p * rnc * rnr) : 0.f;
            float dve = act ? dvr : 0.f;
            aA.x = fmaf(dve, hA.x, aA.x); aA.y = fmaf(dve, hA.y, aA.y);
            aA.z = fmaf(dve, hA.z, aA.z); aA.w = fmaf(dve, hA.w, aA.w);
            aB.x = fmaf(dve, hB.x, aB.x); aB.y = fmaf(dve, hB.y, aB.y);
            aB.z = fmaf(dve, hB.z, aB.z); aB.w = fmaf(dve, hB.w, aB.w);
            nA.x = fmaf(w, hA.x, nA.x); nA.y = fmaf(w, hA.y, nA.y);
            nA.z = fmaf(w, hA.z, nA.z); nA.w = fmaf(w, hA.w, nA.w);
            nB.x = fmaf(w, hB.x, nB.x); nB.y = fmaf(w, hB.y, nB.y);
            nB.z = fmaf(w, hB.z, nB.z); nB.w = fmaf(w, hB.w, nB.w);
            denom += w;
        }
    }
#pragma unroll
    for (int d = 8; d < 64; d <<= 1) {
        aA.x += __shfl_xor(aA.x, d, 64); aA.y += __shfl_xor(aA.y, d, 64);
        aA.z += __shfl_xor(aA.z, d, 64); aA.w += __shfl_xor(aA.w, d, 64);
        aB.x += __shfl_xor(aB.x, d, 64); aB.y += __shfl_xor(aB.y, d, 64);
        aB.z += __shfl_xor(aB.z, d, 64); aB.w += __shfl_xor(aB.w, d, 64);
        nA.x += __shfl_xor(nA.x, d, 64); nA.y += __shfl_xor(nA.y, d, 64);
        nA.z += __shfl_xor(nA.z, d, 64); nA.w += __shfl_xor(nA.w, d, 64);
        nB.x += __shfl_xor(nB.x, d, 64); nB.y += __shfl_xor(nB.y, d, 64);
        nB.z += __shfl_xor(nB.z, d, 64); nB.w += __shfl_xor(nB.w, d, 64);
        denom += __shfl_xor(denom, d, 64);
    }
    if (g == 0) {
        float4* op = (float4*)(agg + (size_t)node * 64);
        op[2 * s]     = make_float4(dc*aA.x, dc*aA.y, dc*aA.z, dc*aA.w);
        op[2 * s + 1] = make_float4(dc*aB.x, dc*aB.y, dc*aB.z, dc*aB.w);
    }
    float inv = 1.0f / denom;
    float cx = 0.f, cy = 0.f;
#pragma unroll
    for (int j = 0; j < 4; j++) {
        float2 wa = ((const float2*)wc)[64 + 8 * s + j];
        float2 wb = ((const float2*)wc)[64 + 8 * s + 4 + j];
        float va = (&nA.x)[j], vb = (&nB.x)[j];
        cx = fmaf(va, wa.x, cx); cx = fmaf(vb, wb.x, cx);
        cy = fmaf(va, wa.y, cy); cy = fmaf(vb, wb.y, cy);
    }
    cx *= inv; cy *= inv;
#pragma unroll
    for (int d = 1; d < 8; d <<= 1) { cx += __shfl_xor(cx, d, 64); cy += __shfl_xor(cy, d, 64); }
    if (lane == 0) yp[node] = make_float2(cx, cy);
}

// ---------------- epilogue: xp fused (H tile + wxs), combined weights ----------------

__global__ __launch_bounds__(256) void k_epi(const float* __restrict__ agg,
    const float* __restrict__ hbuf, const float2* __restrict__ yp,
    const float* __restrict__ pre, const float* __restrict__ wx,
    const float* __restrict__ bx, const float* __restrict__ bc,
    float* __restrict__ y, int n, int ntiles)
{
    __shared__ float W0s[4096], W1s[4096], wxs[4096];
    __shared__ float c0s[64], c1s[64], bxs[64], us[256], vs[4], bcs[2];
    __shared__ float A[32][68], H[32][68];
    int t = threadIdx.x;
    for (int i = t; i < 4096; i += 256) { W0s[i] = pre[i]; W1s[i] = pre[4096 + i]; wxs[i] = wx[i]; }
    if (t < 64) { c0s[t] = pre[8192 + t]; c1s[t] = pre[8256 + t]; bxs[t] = bx[t]; }
    us[t] = pre[8320 + t];
    if (t < 4) vs[t] = pre[8576 + t];
    if (t < 2) bcs[t] = bc[t];
    __syncthreads();
    int cg = t & 15, rg = t >> 4;
    for (int tile = blockIdx.x; tile < ntiles; tile += gridDim.x) {
        int row0 = tile * 32;
        load_rows32(agg,  row0, n, A, t);
        load_rows32(hbuf, row0, n, H, t);
        __syncthreads();
        int r0g = row0 + 2 * rg, r1g = r0g + 1;
        float xp0[4], xp1[4];
        gemm_core(H, wxs, bxs, rg, cg, xp0, xp1);
#pragma unroll
        for (int j = 0; j < 4; j++) { xp0[j] = fast_tanh(xp0[j]); xp1[j] = fast_tanh(xp1[j]); }
        float a0[4], a1[4];
        gemm_core(A, W0s, c0s, rg, cg, a0, a1);
        float l00 = 0.f, l01 = 0.f;
#pragma unroll
        for (int j = 0; j < 4; j++) {
            l00 = fmaf(fast_tanh(a0[j]), xp0[j], l00);
            l01 = fmaf(fast_tanh(a1[j]), xp1[j], l01);
        }
        gemm_core(A, W1s, c1s, rg, cg, a0, a1);
        float l10 = 0.f, l11 = 0.f;
#pragma unroll
        for (int j = 0; j < 4; j++) {
            l10 = fmaf(fast_tanh(a0[j]), xp0[j], l10);
            l11 = fmaf(fast_tanh(a1[j]), xp1[j], l11);
        }
        float4 av0 = *(const float4*)&A[2 * rg][4 * cg];
        float4 av1 = *(const float4*)&A[2 * rg + 1][4 * cg];
        float za0=0.f, za1=0.f, zb0=0.f, zb1=0.f;
        float zc0=0.f, zc1=0.f, zd0=0.f, zd1=0.f;
#pragma unroll
        for (int j = 0; j < 4; j++) {
            int k = 4 * cg + j;
            float u0c0 = us[k * 2], u0c1 = us[k * 2 + 1];
            float u1c0 = us[128 + k * 2], u1c1 = us[128 + k * 2 + 1];
            float p0 = (&av0.x)[j], p1 = (&av1.x)[j];
            za0 = fmaf(p0, u0c0, za0); za1 = fmaf(p0, u0c1, za1);
            zb0 = fmaf(p0, u1c0, zb0); zb1 = fmaf(p0, u1c1, zb1);
            zc0 = fmaf(p1, u0c0, zc0); zc1 = fmaf(p1, u0c1, zc1);
            zd0 = fmaf(p1, u1c0, zd0); zd1 = fmaf(p1, u1c1, zd1);
        }
#pragma unroll
        for (int d = 1; d < 16; d <<= 1) {
            l00 += __shfl_xor(l00, d, 64); l01 += __shfl_xor(l01, d, 64);
            l10 += __shfl_xor(l10, d, 64); l11 += __shfl_xor(l11, d, 64);
            za0 += __shfl_xor(za0, d, 64); za1 += __shfl_xor(za1, d, 64);
            zb0 += __shfl_xor(zb0, d, 64); zb1 += __shfl_xor(zb1, d, 64);
            zc0 += __shfl_xor(zc0, d, 64); zc1 += __shfl_xor(zc1, d, 64);
            zd0 += __shfl_xor(zd0, d, 64); zd1 += __shfl_xor(zd1, d, 64);
        }
        if (cg == 0) {
            if (r0g < n) {
                float mx = fmaxf(l00, l10);
                float e0 = __expf(l00 - mx), e1 = __expf(l10 - mx);
                float inv = 1.0f / (e0 + e1);
                float s0 = e0 * inv, s1 = e1 * inv;
                float2 ypv = yp[r0g];
                float y0v = s0 * (za0 + vs[0]) + s1 * (zb0 + vs[2]) + ypv.x + bcs[0];
                float y1v = s0 * (za1 + vs[1]) + s1 * (zb1 + vs[3]) + ypv.y + bcs[1];
                *(float2*)&y[(size_t)r0g * 2] = make_float2(y0v, y1v);
            }
            if (r1g < n) {
                float mx = fmaxf(l01, l11);
                float e0 = __expf(l01 - mx), e1 = __expf(l11 - mx);
                float inv = 1.0f / (e0 + e1);
                float s0 = e0 * inv, s1 = e1 * inv;
                float2 ypv = yp[r1g];
                float y0v = s0 * (zc0 + vs[0]) + s1 * (zd0 + vs[2]) + ypv.x + bcs[0];
                float y1v = s0 * (zc1 + vs[1]) + s1 * (zd1 + vs[3]) + ypv.y + bcs[1];
                *(float2*)&y[(size_t)r1g * 2] = make_float2(y0v, y1v);
            }
        }
        __syncthreads();
    }
}

extern "C" void kernel_launch(void* const* d_in, const int* in_sizes, int n_in,
                              void* d_out, int out_size, void* d_ws, size_t ws_size,
                              hipStream_t stream)
{
    const float* x    = (const float*)d_in[0];
    const int*   ei   = (const int*)d_in[1];
    const float* w1   = (const float*)d_in[2];
    const float* b1   = (const float*)d_in[3];
    const float* w2   = (const float*)d_in[4];
    const float* b2   = (const float*)d_in[5];
    const float* w3   = (const float*)d_in[6];
    const float* b3   = (const float*)d_in[7];
    const float* wg1  = (const float*)d_in[8];
    const float* bg1  = (const float*)d_in[9];
    const float* wg2  = (const float*)d_in[10];
    const float* bg2  = (const float*)d_in[11];
    const float* beta = (const float*)d_in[12];
    const float* wf   = (const float*)d_in[13];
    const float* bf   = (const float*)d_in[14];
    const float* wx   = (const float*)d_in[15];
    const float* bx   = (const float*)d_in[16];
    const float* wc   = (const float*)d_in[17];
    const float* bc   = (const float*)d_in[18];
    float* y = (float*)d_out;

    int n = in_sizes[0] / 64;     // 100000
    int e = in_sizes[1] / 2;      // 1600000
    const int* row = ei;
    const int* col = ei + e;

    // workspace ~34MB
    char* p = (char*)d_ws;
    auto alloc = [&](size_t bytes) { char* q = p; p += (bytes + 255) & ~(size_t)255; return q; };
    float*  h    = (float*)alloc((size_t)n * 64 * 4);    // 25.6MB (pairs -> h)
    int*    csr  = (int*)alloc((size_t)e * 4);           // 6.4MB
    float2* nrm2 = (float2*)alloc((size_t)n * 8);        // 0.8MB
    int*    arr  = (int*)alloc((size_t)(n + 1) * 4);     // 0.4MB
    float2* yp   = (float2*)alloc((size_t)n * 8);        // 0.8MB
    float*  pre  = (float*)alloc(8704 * 4);              // combined weights
    int*    bhist = (int*)alloc(256 * 4);
    int*    bbase = (int*)alloc(256 * 4);
    int*    bcur  = (int*)alloc(256 * 4);

    // pairs buffer (12.8MB) aliases h: consumed by k_fill3 before k_mlp writes h.
    int2* pairs = (int2*)h;
    // agg reuses x's buffer (x dead after k_mlp; harness restores d_in).
    float* agg = (float*)d_in[0];

    int ntiles = (n + 31) / 32;            // 3125 32-row tiles
    int nbk = (n + 511) >> 9;              // 196 buckets (col>>9)
    int nsct = (e + SCT - 1) / SCT;        // 196 scatter tiles

    k_pre<<<1, 256, 0, stream>>>(wg1, bg1, wg2, bg2, wf, bf, wc, pre);
    k_zero<<<1, 256, 0, stream>>>(bhist, 256);
    k_bhist<<<nsct, 256, 0, stream>>>(col, bhist, e);
    k_bscan<<<1, 256, 0, stream>>>(bhist, bbase, bcur);
    k_bscatter2<<<nsct, 256, 0, stream>>>(row, col, bcur, pairs, e, nbk);
    k_fill3<<<nbk, 256, 0, stream>>>(pairs, bbase, bhist, arr, csr, n);
    k_mlp<<<ntiles, 256, 0, stream>>>(x, w1, b1, w2, b2, w3, b3, arr, h, nrm2, n);
    k_gather<<<(n + 3) / 4, 256, 0, stream>>>(h, arr, csr, nrm2, beta, wc, agg, yp, n);
    k_epi<<<1024, 256, 0, stream>>>(agg, h, yp, pre, wx, bx, bc, y, n, ntiles);
}